// Round 1
// baseline (1026.141 us; speedup 1.0000x reference)
//
#include <hip/hip_runtime.h>
#include <math.h>

// SpGraphAttentionLayer on MI355X.
// Decomposition: M_src[h]=W_src[h]@proj[h], M_tgt[h]=W_tgt[h]@proj[h];
// hsrc=input@M_srcT, htgt=input@M_tgtT (node tables, fp32);
// score[h,e] = in[src]·asrc[h] + in[tgt]·atgt[h] + emb[e]·arel[h];
// head_out[h,n] = rowsum_h[n]*hsrc[h,n] + sum_e ee*htgt[h,tgt] + W_rel[h]@(sum_e ee*emb[e]);
// out = elu( (sum_h w_h*head_out[h,n]) / max(rowsum_3[n],1e-12) ).
// Edges aggregated via CSR built with counting sort (no float atomics in k4).

#define NHEAD 4

__global__ __launch_bounds__(256) void k1_prep(
    const float* __restrict__ proj, const float* __restrict__ W,
    const float* __restrict__ a, const float* __restrict__ hw,
    float* __restrict__ M_src, float* __restrict__ M_tgt,
    float* __restrict__ asrc, float* __restrict__ atgt, float* __restrict__ arel,
    float* __restrict__ W_relT, float* __restrict__ wsoft,
    float* __restrict__ orth_part)
{
    __shared__ float projS[128*132];
    __shared__ float WS[32*132];
    __shared__ float tS[128];
    __shared__ float red[256];
    const int h = blockIdx.x;
    const int part = blockIdx.y;
    const int z = blockIdx.z;
    const int tid = threadIdx.x;
    const float* projH = proj + h*(128*128);
    const float* WH = W + h*(128*320);
    const float* aH = a + h*128;

    {   // stage proj[h] into LDS, padded stride 132 (16B-aligned rows, conflict-free)
        const float4* p4 = (const float4*)projH;
        for (int idx = tid; idx < 4096; idx += 256)
            *(float4*)&projS[(idx>>5)*132 + (idx&31)*4] = p4[idx];
    }

    if (part < 2) {
        const int koff = part ? 128 : 0;
        for (int idx = tid; idx < 1024; idx += 256) {
            const int ol = idx>>5, jq = idx&31;
            *(float4*)&WS[ol*132 + jq*4] = *(const float4*)&WH[(z*32+ol)*320 + koff + jq*4];
        }
        __syncthreads();
        float* Mout = (part ? M_tgt : M_src) + h*16384;
        for (int idx = tid; idx < 1024; idx += 256) {
            const int ol = idx>>5, jq = idx&31;
            float4 acc; acc.x=0.f; acc.y=0.f; acc.z=0.f; acc.w=0.f;
            for (int i = 0; i < 128; ++i) {
                const float wv = WS[ol*132 + i];
                const float4 pv = *(const float4*)&projS[i*132 + jq*4];
                acc.x += wv*pv.x; acc.y += wv*pv.y; acc.z += wv*pv.z; acc.w += wv*pv.w;
            }
            *(float4*)&Mout[(z*32+ol)*128 + jq*4] = acc;
        }
        if (z == 0) {
            if (tid < 128) {
                float s = 0.f;
                for (int o = 0; o < 128; ++o) s += aH[o]*WH[o*320 + koff + tid];
                tS[tid] = s;
            }
            __syncthreads();
            if (tid < 128) {
                float s = 0.f;
                for (int i = 0; i < 128; ++i) s += tS[i]*projS[i*132 + tid];
                (part ? atgt : asrc)[h*128 + tid] = s;
            }
        }
    } else {
        __syncthreads();
        // orth partial: quarter of the (i,k) space per z-block
        float local = 0.f;
        const int base = z*4096;
        for (int idx = base + tid; idx < base + 4096; idx += 256) {
            const int i = idx>>7, k = idx&127;
            float s = 0.f;
            for (int q = 0; q < 32; ++q) {
                const float4 pi = *(const float4*)&projS[i*132 + q*4];
                const float4 pk = *(const float4*)&projS[k*132 + q*4];
                s += pi.x*pk.x + pi.y*pk.y + pi.z*pk.z + pi.w*pk.w;
            }
            if (i == k) s -= 1.f;
            local += s*s;
        }
        red[tid] = local;
        __syncthreads();
        for (int st = 128; st > 0; st >>= 1) {
            if (tid < st) red[tid] += red[tid+st];
            __syncthreads();
        }
        if (tid == 0) atomicAdd(&orth_part[h], red[0]);
        if (z == 0) {
            if (tid < 64) {
                float s = 0.f;
                for (int o = 0; o < 128; ++o) s += aH[o]*WH[o*320 + 256 + tid];
                arel[h*64 + tid] = s;
            }
            for (int idx = tid; idx < 8192; idx += 256) {
                const int r = idx>>7, o = idx&127;
                W_relT[h*8192 + r*128 + o] = WH[o*320 + 256 + r];
            }
            if (h == 0 && tid == 0) {
                const float m = fmaxf(fmaxf(hw[0],hw[1]), fmaxf(hw[2],hw[3]));
                const float e0=expf(hw[0]-m), e1=expf(hw[1]-m), e2=expf(hw[2]-m), e3=expf(hw[3]-m);
                const float s = e0+e1+e2+e3;
                wsoft[0]=e0/s; wsoft[1]=e1/s; wsoft[2]=e2/s; wsoft[3]=e3/s;
            }
        }
    }
}

// hsrc/htgt tables: per (64-node tile, head, src/tgt): out[n][h*128+o] = input[n]·M[h][o][:]
__global__ __launch_bounds__(256) void k2_gemm(
    const float* __restrict__ input, const float* __restrict__ M_src, const float* __restrict__ M_tgt,
    float* __restrict__ hsrc_tbl, float* __restrict__ htgt_tbl, int N)
{
    __shared__ float4 MS4[128*33];   // M[h], rows padded to 33 f4 (132 floats)
    __shared__ float4 inS4[64*33];
    const int tid = threadIdx.x;
    const int h = blockIdx.y;
    const float* M = (blockIdx.z==0) ? M_src : M_tgt;
    float* outT = (blockIdx.z==0) ? hsrc_tbl : htgt_tbl;
    const int n0 = blockIdx.x*64;

    const float4* Mf4 = (const float4*)(M + h*16384);
    for (int idx = tid; idx < 4096; idx += 256)
        MS4[(idx>>5)*33 + (idx&31)] = Mf4[idx];
    const float4* inf4 = (const float4*)input;
    for (int idx = tid; idx < 2048; idx += 256) {
        const int r = idx>>5, jq = idx&31;
        const int n = n0 + r;
        float4 v; v.x=0.f; v.y=0.f; v.z=0.f; v.w=0.f;
        if (n < N) v = inf4[(size_t)n*32 + jq];
        inS4[r*33 + jq] = v;
    }
    __syncthreads();

    const int lane = tid & 63, w = tid >> 6;
    float acc0[16], acc1[16];
    #pragma unroll
    for (int rr = 0; rr < 16; ++rr) { acc0[rr]=0.f; acc1[rr]=0.f; }
    for (int jq = 0; jq < 32; ++jq) {
        const float4 m0 = MS4[lane*33 + jq];
        const float4 m1 = MS4[(lane+64)*33 + jq];
        #pragma unroll
        for (int rr = 0; rr < 16; ++rr) {
            const float4 iv = inS4[(w*16+rr)*33 + jq];
            acc0[rr] += iv.x*m0.x + iv.y*m0.y + iv.z*m0.z + iv.w*m0.w;
            acc1[rr] += iv.x*m1.x + iv.y*m1.y + iv.z*m1.z + iv.w*m1.w;
        }
    }
    #pragma unroll
    for (int rr = 0; rr < 16; ++rr) {
        const int n = n0 + w*16 + rr;
        if (n < N) {
            float* base = outT + (size_t)n*512 + h*128;
            base[lane] = acc0[rr];
            base[lane+64] = acc1[rr];
        }
    }
}

// per-node score partials: s_src[n][h]=in[n]·asrc[h], s_tgt[n][h]=in[n]·atgt[h]
__global__ __launch_bounds__(256) void k2b_scores(
    const float* __restrict__ input, const float* __restrict__ asrc, const float* __restrict__ atgt,
    float* __restrict__ s_src, float* __restrict__ s_tgt, int N)
{
    __shared__ float aS[512], tS[512];
    const int tid = threadIdx.x;
    for (int idx = tid; idx < 512; idx += 256) { aS[idx] = asrc[idx]; tS[idx] = atgt[idx]; }
    __syncthreads();
    const int n = blockIdx.x*256 + tid;
    if (n >= N) return;
    const float4* inr = (const float4*)(input + (size_t)n*128);
    float ss[4] = {0.f,0.f,0.f,0.f}, st[4] = {0.f,0.f,0.f,0.f};
    for (int q = 0; q < 32; ++q) {
        const float4 v = inr[q];
        #pragma unroll
        for (int hh = 0; hh < 4; ++hh) {
            const float4 av = *(const float4*)&aS[hh*128 + q*4];
            const float4 tv = *(const float4*)&tS[hh*128 + q*4];
            ss[hh] += v.x*av.x + v.y*av.y + v.z*av.z + v.w*av.w;
            st[hh] += v.x*tv.x + v.y*tv.y + v.z*tv.z + v.w*tv.w;
        }
    }
    float4 o1; o1.x=ss[0]; o1.y=ss[1]; o1.z=ss[2]; o1.w=ss[3];
    float4 o2; o2.x=st[0]; o2.y=st[1]; o2.z=st[2]; o2.w=st[3];
    *(float4*)(s_src + (size_t)n*4) = o1;
    *(float4*)(s_tgt + (size_t)n*4) = o2;
}

// per-edge: edge_e = exp(-leaky(score)); rowsum atomics; degree histogram
__global__ __launch_bounds__(256) void k3_edges(
    const int* __restrict__ edge, const int* __restrict__ nhop,
    const float* __restrict__ emb1, const float* __restrict__ emb2,
    const float* __restrict__ s_src, const float* __restrict__ s_tgt,
    const float* __restrict__ arel,
    float* __restrict__ edge_e, float* __restrict__ rowsum, int* __restrict__ deg,
    int E1, int E2)
{
    __shared__ float arelS[256];
    const int tid = threadIdx.x;
    arelS[tid] = arel[tid];
    __syncthreads();
    const int E = E1 + E2;
    const int e = blockIdx.x*256 + tid;
    if (e >= E) return;
    int src, tgt; const float* er;
    if (e < E1) { src = edge[e]; tgt = edge[E1+e]; er = emb1 + (size_t)e*64; }
    else { const int e2 = e-E1; src = nhop[e2]; tgt = nhop[E2+e2]; er = emb2 + (size_t)e2*64; }
    float sr[4] = {0.f,0.f,0.f,0.f};
    const float4* er4 = (const float4*)er;
    for (int q = 0; q < 16; ++q) {
        const float4 v = er4[q];
        #pragma unroll
        for (int hh = 0; hh < 4; ++hh) {
            const float4 av = *(const float4*)&arelS[hh*64 + q*4];
            sr[hh] += v.x*av.x + v.y*av.y + v.z*av.z + v.w*av.w;
        }
    }
    const float4 s4 = *(const float4*)(s_src + (size_t)src*4);
    const float4 t4 = *(const float4*)(s_tgt + (size_t)tgt*4);
    const float sv[4] = {s4.x,s4.y,s4.z,s4.w};
    const float tv[4] = {t4.x,t4.y,t4.z,t4.w};
    float ee[4];
    #pragma unroll
    for (int hh = 0; hh < 4; ++hh) {
        const float sc = sv[hh] + tv[hh] + sr[hh];
        const float p = (sc > 0.f) ? -sc : (-0.2f*sc);
        ee[hh] = expf(p);
        atomicAdd(&rowsum[(size_t)src*4 + hh], ee[hh]);
    }
    float4 eo; eo.x=ee[0]; eo.y=ee[1]; eo.z=ee[2]; eo.w=ee[3];
    *(float4*)(edge_e + (size_t)e*4) = eo;
    atomicAdd(&deg[src], 1);
}

__global__ __launch_bounds__(1024) void k_scan(const int* __restrict__ deg, int* __restrict__ offsets, int N)
{
    __shared__ int s[1024];
    __shared__ int carry;
    const int tid = threadIdx.x;
    if (tid == 0) carry = 0;
    __syncthreads();
    for (int base = 0; base < N; base += 1024) {
        const int v = (base+tid < N) ? deg[base+tid] : 0;
        s[tid] = v;
        __syncthreads();
        for (int st = 1; st < 1024; st <<= 1) {
            const int t = (tid >= st) ? s[tid-st] : 0;
            __syncthreads();
            s[tid] += t;
            __syncthreads();
        }
        const int c = carry;
        if (base+tid < N) offsets[base+tid] = c + s[tid] - v;
        __syncthreads();
        if (tid == 1023) carry = c + s[1023];
        __syncthreads();
    }
    if (tid == 0) offsets[N] = carry;
}

__global__ __launch_bounds__(256) void k_fill(
    const int* __restrict__ edge, const int* __restrict__ nhop,
    const int* __restrict__ offsets, int* __restrict__ cursor, int* __restrict__ csr,
    int E1, int E2)
{
    const int E = E1+E2;
    const int e = blockIdx.x*256 + threadIdx.x;
    if (e >= E) return;
    const int src = (e < E1) ? edge[e] : nhop[e-E1];
    const int pos = atomicAdd(&cursor[src], 1);
    csr[offsets[src] + pos] = e;
}

// per-node wave: gather htgt/edge_e/emb per CSR edge, accumulate head-combined pout + per-head semb
__global__ __launch_bounds__(256) void k4_gather(
    const int* __restrict__ edge, const int* __restrict__ nhop,
    const float* __restrict__ emb1, const float* __restrict__ emb2,
    const float* __restrict__ edge_e, const int* __restrict__ offsets, const int* __restrict__ csr,
    const float* __restrict__ hsrc_tbl, const float* __restrict__ htgt_tbl,
    const float* __restrict__ rowsum, const float* __restrict__ wsoft,
    float* __restrict__ pout, float* __restrict__ semb_t,
    int N, int E1, int E2)
{
    const int lane = threadIdx.x & 63;
    const int n = blockIdx.x*4 + (threadIdx.x >> 6);
    if (n >= N) return;
    const float4 rs4 = *(const float4*)(rowsum + (size_t)n*4);
    const float rs[4] = {rs4.x, rs4.y, rs4.z, rs4.w};
    const float* hs = hsrc_tbl + (size_t)n*512;
    float acc[4][2];
    #pragma unroll
    for (int hh = 0; hh < 4; ++hh) {
        acc[hh][0] = rs[hh]*hs[hh*128 + lane];
        acc[hh][1] = rs[hh]*hs[hh*128 + 64 + lane];
    }
    float semb[4] = {0.f,0.f,0.f,0.f};
    const int start = offsets[n], end = offsets[n+1];
    for (int cb = start; cb < end; cb += 64) {
        const int cnt = (end - cb < 64) ? (end - cb) : 64;
        int eL = 0, tgtL = 0;
        float eeL0=0.f, eeL1=0.f, eeL2=0.f, eeL3=0.f;
        if (cb + lane < end) {
            eL = csr[cb + lane];
            tgtL = (eL < E1) ? edge[E1 + eL] : nhop[E2 + (eL - E1)];
            const float4 t = *(const float4*)(edge_e + (size_t)eL*4);
            eeL0=t.x; eeL1=t.y; eeL2=t.z; eeL3=t.w;
        }
        for (int i = 0; i < cnt; ++i) {
            const int e   = __shfl(eL, i);
            const int tgt = __shfl(tgtL, i);
            const float e0 = __shfl(eeL0, i);
            const float e1 = __shfl(eeL1, i);
            const float e2 = __shfl(eeL2, i);
            const float e3 = __shfl(eeL3, i);
            const float* er = (e < E1) ? (emb1 + (size_t)e*64) : (emb2 + (size_t)(e-E1)*64);
            const float ev = er[lane];
            semb[0] += e0*ev; semb[1] += e1*ev; semb[2] += e2*ev; semb[3] += e3*ev;
            const float* ht = htgt_tbl + (size_t)tgt*512;
            acc[0][0] += e0*ht[lane];      acc[0][1] += e0*ht[64+lane];
            acc[1][0] += e1*ht[128+lane];  acc[1][1] += e1*ht[192+lane];
            acc[2][0] += e2*ht[256+lane];  acc[2][1] += e2*ht[320+lane];
            acc[3][0] += e3*ht[384+lane];  acc[3][1] += e3*ht[448+lane];
        }
    }
    const float w0=wsoft[0], w1=wsoft[1], w2=wsoft[2], w3=wsoft[3];
    pout[(size_t)n*128 + lane]      = w0*acc[0][0] + w1*acc[1][0] + w2*acc[2][0] + w3*acc[3][0];
    pout[(size_t)n*128 + 64 + lane] = w0*acc[0][1] + w1*acc[1][1] + w2*acc[2][1] + w3*acc[3][1];
    #pragma unroll
    for (int hh = 0; hh < 4; ++hh)
        semb_t[(size_t)n*256 + hh*64 + lane] = semb[hh];
}

// W_rel matvec on semb + finalize: divide by clipped rowsum[h=3], ELU; also orth scalar
__global__ __launch_bounds__(256) void k5_final(
    const float* __restrict__ W_relT, const float* __restrict__ semb_t,
    const float* __restrict__ rowsum, const float* __restrict__ wsoft,
    const float* __restrict__ orth_part,
    float* __restrict__ out, int N)
{
    __shared__ float4 WtS[8192];     // 4*64*128 floats = 128KB
    __shared__ float sembS[16*256];  // 16KB
    __shared__ float wsS[4];
    const int tid = threadIdx.x;
    if (blockIdx.x == 0 && tid == 0)
        out[(size_t)N*128] = 0.01f*(sqrtf(orth_part[0])+sqrtf(orth_part[1])+sqrtf(orth_part[2])+sqrtf(orth_part[3]));
    const float4* Wt4 = (const float4*)W_relT;
    for (int idx = tid; idx < 8192; idx += 256) WtS[idx] = Wt4[idx];
    const int n0 = blockIdx.x*16;
    const float4* se4 = (const float4*)semb_t;
    for (int idx = tid; idx < 1024; idx += 256) {
        const int rl = idx >> 6;
        const int q  = idx & 63;
        const int n = n0 + rl;
        float4 v; v.x=0.f; v.y=0.f; v.z=0.f; v.w=0.f;
        if (n < N) v = se4[(size_t)n*64 + q];
        *(float4*)&sembS[rl*256 + q*4] = v;
    }
    if (tid < 4) wsS[tid] = wsoft[tid];
    __syncthreads();

    const int o4 = tid & 31;           // output f4 index: o = o4*4..o4*4+3
    const int rbase = (tid >> 5)*2;    // this thread's 2 local rows
    float4 a0; a0.x=0.f; a0.y=0.f; a0.z=0.f; a0.w=0.f;
    float4 a1 = a0;
    for (int hh = 0; hh < 4; ++hh) {
        const float wh = wsS[hh];
        for (int r = 0; r < 64; ++r) {
            const float4 wt = WtS[(hh*64+r)*32 + o4];
            const float s0 = sembS[rbase*256 + hh*64 + r] * wh;
            const float s1 = sembS[(rbase+1)*256 + hh*64 + r] * wh;
            a0.x += wt.x*s0; a0.y += wt.y*s0; a0.z += wt.z*s0; a0.w += wt.w*s0;
            a1.x += wt.x*s1; a1.y += wt.y*s1; a1.z += wt.z*s1; a1.w += wt.w*s1;
        }
    }
    #pragma unroll
    for (int k = 0; k < 2; ++k) {
        const int n = n0 + rbase + k;
        if (n >= N) continue;
        const float rinv = 1.0f / fmaxf(rowsum[(size_t)n*4 + 3], 1e-12f);
        float* op = out + (size_t)n*128 + o4*4;
        const float4 p = *(const float4*)op;
        const float4 ad = k ? a1 : a0;
        float v0 = (p.x + ad.x)*rinv;
        float v1 = (p.y + ad.y)*rinv;
        float v2 = (p.z + ad.z)*rinv;
        float v3 = (p.w + ad.w)*rinv;
        v0 = (v0 > 0.f) ? v0 : expm1f(v0);
        v1 = (v1 > 0.f) ? v1 : expm1f(v1);
        v2 = (v2 > 0.f) ? v2 : expm1f(v2);
        v3 = (v3 > 0.f) ? v3 : expm1f(v3);
        float4 r4; r4.x=v0; r4.y=v1; r4.z=v2; r4.w=v3;
        *(float4*)op = r4;
    }
}

extern "C" void kernel_launch(void* const* d_in, const int* in_sizes, int n_in,
                              void* d_out, int out_size, void* d_ws, size_t ws_size,
                              hipStream_t stream)
{
    const float* input = (const float*)d_in[0];
    const int*   edge  = (const int*)d_in[1];
    const float* emb1  = (const float*)d_in[2];
    const int*   nhop  = (const int*)d_in[3];
    const float* emb2  = (const float*)d_in[4];
    const float* proj  = (const float*)d_in[5];
    const float* W     = (const float*)d_in[6];
    const float* a     = (const float*)d_in[7];
    const float* hw    = (const float*)d_in[8];
    float* out = (float*)d_out;

    const int N  = in_sizes[0] / 128;
    const int E1 = in_sizes[1] / 2;
    const int E2 = in_sizes[3] / 2;
    const int E  = E1 + E2;
    (void)n_in; (void)out_size; (void)ws_size;

    char* wsb = (char*)d_ws;
    size_t off = 0;
    auto alloc = [&](size_t bytes) -> char* {
        char* p = wsb + off;
        off += (bytes + 255) & ~(size_t)255;
        return p;
    };
    float* hsrc_tbl = (float*)alloc((size_t)N*512*4);
    float* htgt_tbl = (float*)alloc((size_t)N*512*4);
    float* edge_e   = (float*)alloc((size_t)E*4*4);
    float* semb_t   = (float*)alloc((size_t)N*256*4);
    float* M_src    = (float*)alloc((size_t)4*16384*4);
    float* M_tgt    = (float*)alloc((size_t)4*16384*4);
    float* W_relT   = (float*)alloc((size_t)4*8192*4);
    float* asrc     = (float*)alloc(512*4);
    float* atgt     = (float*)alloc(512*4);
    float* arel     = (float*)alloc(256*4);
    float* s_src    = (float*)alloc((size_t)N*4*4);
    float* s_tgt    = (float*)alloc((size_t)N*4*4);
    float* wsoft    = (float*)alloc(4*4);
    float* rowsum   = (float*)alloc((size_t)N*4*4);
    float* orth_part= (float*)alloc(4*4);
    int* deg        = (int*)alloc((size_t)N*4);
    int* cursor     = (int*)alloc((size_t)N*4);
    int* offsets    = (int*)alloc((size_t)(N+1)*4);
    int* csr        = (int*)alloc((size_t)E*4);

    hipMemsetAsync(rowsum, 0, (size_t)N*4*4, stream);
    hipMemsetAsync(orth_part, 0, 4*4, stream);
    hipMemsetAsync(deg, 0, (size_t)N*4, stream);
    hipMemsetAsync(cursor, 0, (size_t)N*4, stream);

    k1_prep<<<dim3(NHEAD,3,4), dim3(256), 0, stream>>>(proj, W, a, hw, M_src, M_tgt,
                                                       asrc, atgt, arel, W_relT, wsoft, orth_part);
    k2_gemm<<<dim3((N+63)/64, NHEAD, 2), dim3(256), 0, stream>>>(input, M_src, M_tgt,
                                                                 hsrc_tbl, htgt_tbl, N);
    k2b_scores<<<dim3((N+255)/256), dim3(256), 0, stream>>>(input, asrc, atgt, s_src, s_tgt, N);
    k3_edges<<<dim3((E+255)/256), dim3(256), 0, stream>>>(edge, nhop, emb1, emb2, s_src, s_tgt,
                                                          arel, edge_e, rowsum, deg, E1, E2);
    k_scan<<<dim3(1), dim3(1024), 0, stream>>>(deg, offsets, N);
    k_fill<<<dim3((E+255)/256), dim3(256), 0, stream>>>(edge, nhop, offsets, cursor, csr, E1, E2);
    k4_gather<<<dim3((N+3)/4), dim3(256), 0, stream>>>(edge, nhop, emb1, emb2, edge_e, offsets, csr,
                                                       hsrc_tbl, htgt_tbl, rowsum, wsoft,
                                                       out, semb_t, N, E1, E2);
    k5_final<<<dim3((N+15)/16), dim3(256), 0, stream>>>(W_relT, semb_t, rowsum, wsoft, orth_part,
                                                        out, N);
}

// Round 2
// 412.182 us; speedup vs baseline: 2.4895x; 2.4895x over previous
//
#include <hip/hip_runtime.h>
#include <math.h>

// SpGraphAttentionLayer on MI355X — round 2: MFMA bf16 for both GEMMs,
// bf16 node tables to halve k4 gather traffic. Scores/edge_e/rowsum stay fp32.
//
// Decomposition: M_src[h]=W_src[h]@proj[h], M_tgt[h]=W_tgt[h]@proj[h] (bf16);
// hsrc=input@M_srcT, htgt=input@M_tgtT (bf16 tables via MFMA);
// score[h,e] = in[src]·asrc[h] + in[tgt]·atgt[h] + emb[e]·arel[h]  (fp32);
// head_out[h,n] = rowsum_h[n]*hsrc[h,n] + sum_e ee*htgt[h,tgt] + W_rel[h]@(sum_e ee*emb[e]);
// out = elu( (sum_h w_h*head_out[h,n]) / max(rowsum_3[n],1e-12) ).
// The W_rel term is deferred: k4 accumulates semb[h]=sum_e ee_h*emb[e] (wsoft folded, bf16),
// k5 does the N x 256 x 128 GEMM via MFMA and fuses the epilogue.

#define NHEAD 4

typedef unsigned short u16;
typedef __attribute__((ext_vector_type(4))) unsigned short u16x4;
typedef __attribute__((ext_vector_type(8))) short bf16x8;
typedef __attribute__((ext_vector_type(4))) float f32x4;

__device__ __forceinline__ float bf2f(u16 v) {
    union { unsigned u; float f; } x; x.u = ((unsigned)v) << 16; return x.f;
}
__device__ __forceinline__ u16 f2bf(float f) {
    union { float f; unsigned u; } x; x.f = f;
    const unsigned r = x.u + 0x7FFFu + ((x.u >> 16) & 1u);
    return (u16)(r >> 16);
}

// input fp32 -> bf16
__global__ __launch_bounds__(256) void kc_bf16(const float* __restrict__ in, u16* __restrict__ out, int total8)
{
    const int i = blockIdx.x*256 + threadIdx.x;
    if (i >= total8) return;
    const float4* p = (const float4*)(in + (size_t)i*8);
    const float4 a = p[0], b = p[1];
    u16 v[8];
    v[0]=f2bf(a.x); v[1]=f2bf(a.y); v[2]=f2bf(a.z); v[3]=f2bf(a.w);
    v[4]=f2bf(b.x); v[5]=f2bf(b.y); v[6]=f2bf(b.z); v[7]=f2bf(b.w);
    *(bf16x8*)(out + (size_t)i*8) = *(bf16x8*)v;
}

__global__ __launch_bounds__(256) void k1_prep(
    const float* __restrict__ proj, const float* __restrict__ W,
    const float* __restrict__ a, const float* __restrict__ hw,
    u16* __restrict__ M_bf,
    float* __restrict__ asrc, float* __restrict__ atgt, float* __restrict__ arel,
    u16* __restrict__ WcatT_bf, float* __restrict__ wsoft,
    float* __restrict__ orth_part)
{
    __shared__ float projS[128*132];
    __shared__ float WS[32*132];
    __shared__ float tS[128];
    __shared__ float red[256];
    const int h = blockIdx.x;
    const int part = blockIdx.y;
    const int z = blockIdx.z;
    const int tid = threadIdx.x;
    const float* projH = proj + h*(128*128);
    const float* WH = W + h*(128*320);
    const float* aH = a + h*128;

    {   // stage proj[h] into LDS, padded stride 132
        const float4* p4 = (const float4*)projH;
        for (int idx = tid; idx < 4096; idx += 256)
            *(float4*)&projS[(idx>>5)*132 + (idx&31)*4] = p4[idx];
    }

    if (part < 2) {
        const int koff = part ? 128 : 0;
        for (int idx = tid; idx < 1024; idx += 256) {
            const int ol = idx>>5, jq = idx&31;
            *(float4*)&WS[ol*132 + jq*4] = *(const float4*)&WH[(z*32+ol)*320 + koff + jq*4];
        }
        __syncthreads();
        u16* Mout = M_bf + ((size_t)(part*4 + h))*16384;
        for (int idx = tid; idx < 1024; idx += 256) {
            const int ol = idx>>5, jq = idx&31;
            float4 acc; acc.x=0.f; acc.y=0.f; acc.z=0.f; acc.w=0.f;
            for (int i = 0; i < 128; ++i) {
                const float wv = WS[ol*132 + i];
                const float4 pv = *(const float4*)&projS[i*132 + jq*4];
                acc.x += wv*pv.x; acc.y += wv*pv.y; acc.z += wv*pv.z; acc.w += wv*pv.w;
            }
            u16x4 pk; pk.x=f2bf(acc.x); pk.y=f2bf(acc.y); pk.z=f2bf(acc.z); pk.w=f2bf(acc.w);
            *(u16x4*)&Mout[(z*32+ol)*128 + jq*4] = pk;
        }
        if (z == 0) {
            if (tid < 128) {
                float s = 0.f;
                for (int o = 0; o < 128; ++o) s += aH[o]*WH[o*320 + koff + tid];
                tS[tid] = s;
            }
            __syncthreads();
            if (tid < 128) {
                float s = 0.f;
                for (int i = 0; i < 128; ++i) s += tS[i]*projS[i*132 + tid];
                (part ? atgt : asrc)[h*128 + tid] = s;
            }
        }
    } else {
        __syncthreads();
        float local = 0.f;
        const int base = z*4096;
        for (int idx = base + tid; idx < base + 4096; idx += 256) {
            const int i = idx>>7, k = idx&127;
            float s = 0.f;
            for (int q = 0; q < 32; ++q) {
                const float4 pi = *(const float4*)&projS[i*132 + q*4];
                const float4 pk = *(const float4*)&projS[k*132 + q*4];
                s += pi.x*pk.x + pi.y*pk.y + pi.z*pk.z + pi.w*pk.w;
            }
            if (i == k) s -= 1.f;
            local += s*s;
        }
        red[tid] = local;
        __syncthreads();
        for (int st = 128; st > 0; st >>= 1) {
            if (tid < st) red[tid] += red[tid+st];
            __syncthreads();
        }
        if (tid == 0) atomicAdd(&orth_part[h], red[0]);
        if (z == 0) {
            if (tid < 64) {
                float s = 0.f;
                for (int o = 0; o < 128; ++o) s += aH[o]*WH[o*320 + 256 + tid];
                arel[h*64 + tid] = s;
            }
            // WcatT[o][h*64+r] = W_rel[h][o][r]  (bf16, row-major in k=h*64+r)
            for (int idx = tid; idx < 8192; idx += 256) {
                const int r = idx & 63, o = idx >> 6;
                WcatT_bf[(size_t)o*256 + h*64 + r] = f2bf(WH[o*320 + 256 + r]);
            }
            if (h == 0 && tid == 0) {
                const float m = fmaxf(fmaxf(hw[0],hw[1]), fmaxf(hw[2],hw[3]));
                const float e0=expf(hw[0]-m), e1=expf(hw[1]-m), e2=expf(hw[2]-m), e3=expf(hw[3]-m);
                const float s = e0+e1+e2+e3;
                wsoft[0]=e0/s; wsoft[1]=e1/s; wsoft[2]=e2/s; wsoft[3]=e3/s;
            }
        }
    }
}

// MFMA bf16 node-table GEMM: 64 nodes/block, 4 waves (wave = 16 rows),
// loop over 8 matrices (src/tgt x 4 heads). B (M_bf) read from L2 as fragments.
__global__ __launch_bounds__(256) void k2_mfma(
    const u16* __restrict__ in_bf, const u16* __restrict__ M_bf,
    u16* __restrict__ hsrc_bf, u16* __restrict__ htgt_bf, int N)
{
    __shared__ u16 DS[64*136];   // D staging, stride 136 (272B, 16B-aligned rows)
    const int tid = threadIdx.x;
    const int w = tid >> 6, lane = tid & 63;
    const int n0 = blockIdx.x*64;
    const int m = lane & 15, kg = lane >> 4;

    bf16x8 fa[4];
    {
        int row = n0 + w*16 + m; if (row >= N) row = N-1;
        const u16* ap = in_bf + (size_t)row*128 + kg*8;
        #pragma unroll
        for (int ks = 0; ks < 4; ++ks) fa[ks] = *(const bf16x8*)(ap + ks*32);
    }

    for (int mat = 0; mat < 8; ++mat) {
        const u16* Mp = M_bf + (size_t)mat*16384;
        f32x4 acc[8];
        #pragma unroll
        for (int nt = 0; nt < 8; ++nt) { acc[nt][0]=0.f; acc[nt][1]=0.f; acc[nt][2]=0.f; acc[nt][3]=0.f; }
        #pragma unroll
        for (int nt = 0; nt < 8; ++nt) {
            const u16* bp = Mp + (size_t)(nt*16 + m)*128 + kg*8;
            #pragma unroll
            for (int ks = 0; ks < 4; ++ks) {
                const bf16x8 fb = *(const bf16x8*)(bp + ks*32);
                acc[nt] = __builtin_amdgcn_mfma_f32_16x16x32_bf16(fa[ks], fb, acc[nt], 0, 0, 0);
            }
        }
        __syncthreads();   // previous coop-store finished
        #pragma unroll
        for (int nt = 0; nt < 8; ++nt) {
            const int o = nt*16 + m;
            const int r0 = w*16 + kg*4;
            #pragma unroll
            for (int r = 0; r < 4; ++r)
                DS[(r0+r)*136 + o] = f2bf(acc[nt][r]);
        }
        __syncthreads();
        const int p = mat >> 2, hh = mat & 3;
        u16* outT = p ? htgt_bf : hsrc_bf;
        for (int idx = tid; idx < 1024; idx += 256) {
            const int row = idx >> 4, seg = idx & 15;
            const int n = n0 + row;
            if (n < N) {
                const bf16x8 v = *(const bf16x8*)&DS[row*136 + seg*8];
                *(bf16x8*)(outT + (size_t)n*512 + hh*128 + seg*8) = v;
            }
        }
    }
}

// per-node score partials (fp32)
__global__ __launch_bounds__(256) void k2b_scores(
    const float* __restrict__ input, const float* __restrict__ asrc, const float* __restrict__ atgt,
    float* __restrict__ s_src, float* __restrict__ s_tgt, int N)
{
    __shared__ float aS[512], tS[512];
    const int tid = threadIdx.x;
    for (int idx = tid; idx < 512; idx += 256) { aS[idx] = asrc[idx]; tS[idx] = atgt[idx]; }
    __syncthreads();
    const int n = blockIdx.x*256 + tid;
    if (n >= N) return;
    const float4* inr = (const float4*)(input + (size_t)n*128);
    float ss[4] = {0.f,0.f,0.f,0.f}, st[4] = {0.f,0.f,0.f,0.f};
    for (int q = 0; q < 32; ++q) {
        const float4 v = inr[q];
        #pragma unroll
        for (int hh = 0; hh < 4; ++hh) {
            const float4 av = *(const float4*)&aS[hh*128 + q*4];
            const float4 tv = *(const float4*)&tS[hh*128 + q*4];
            ss[hh] += v.x*av.x + v.y*av.y + v.z*av.z + v.w*av.w;
            st[hh] += v.x*tv.x + v.y*tv.y + v.z*tv.z + v.w*tv.w;
        }
    }
    float4 o1; o1.x=ss[0]; o1.y=ss[1]; o1.z=ss[2]; o1.w=ss[3];
    float4 o2; o2.x=st[0]; o2.y=st[1]; o2.z=st[2]; o2.w=st[3];
    *(float4*)(s_src + (size_t)n*4) = o1;
    *(float4*)(s_tgt + (size_t)n*4) = o2;
}

__global__ __launch_bounds__(256) void k3_edges(
    const int* __restrict__ edge, const int* __restrict__ nhop,
    const float* __restrict__ emb1, const float* __restrict__ emb2,
    const float* __restrict__ s_src, const float* __restrict__ s_tgt,
    const float* __restrict__ arel,
    float* __restrict__ edge_e, float* __restrict__ rowsum, int* __restrict__ deg,
    int E1, int E2)
{
    __shared__ float arelS[256];
    const int tid = threadIdx.x;
    arelS[tid] = arel[tid];
    __syncthreads();
    const int E = E1 + E2;
    const int e = blockIdx.x*256 + tid;
    if (e >= E) return;
    int src, tgt; const float* er;
    if (e < E1) { src = edge[e]; tgt = edge[E1+e]; er = emb1 + (size_t)e*64; }
    else { const int e2 = e-E1; src = nhop[e2]; tgt = nhop[E2+e2]; er = emb2 + (size_t)e2*64; }
    float sr[4] = {0.f,0.f,0.f,0.f};
    const float4* er4 = (const float4*)er;
    for (int q = 0; q < 16; ++q) {
        const float4 v = er4[q];
        #pragma unroll
        for (int hh = 0; hh < 4; ++hh) {
            const float4 av = *(const float4*)&arelS[hh*64 + q*4];
            sr[hh] += v.x*av.x + v.y*av.y + v.z*av.z + v.w*av.w;
        }
    }
    const float4 s4 = *(const float4*)(s_src + (size_t)src*4);
    const float4 t4 = *(const float4*)(s_tgt + (size_t)tgt*4);
    const float sv[4] = {s4.x,s4.y,s4.z,s4.w};
    const float tv[4] = {t4.x,t4.y,t4.z,t4.w};
    float ee[4];
    #pragma unroll
    for (int hh = 0; hh < 4; ++hh) {
        const float sc = sv[hh] + tv[hh] + sr[hh];
        const float p = (sc > 0.f) ? -sc : (-0.2f*sc);
        ee[hh] = expf(p);
        atomicAdd(&rowsum[(size_t)src*4 + hh], ee[hh]);
    }
    float4 eo; eo.x=ee[0]; eo.y=ee[1]; eo.z=ee[2]; eo.w=ee[3];
    *(float4*)(edge_e + (size_t)e*4) = eo;
    atomicAdd(&deg[src], 1);
}

// single-block scan, shfl-based (4 barriers / 4096 elems)
__global__ __launch_bounds__(1024) void k_scan(const int* __restrict__ deg, int* __restrict__ offsets, int N)
{
    __shared__ int wsumS[16];
    __shared__ int carry;
    const int tid = threadIdx.x;
    const int lane = tid & 63, wid = tid >> 6;
    if (tid == 0) carry = 0;
    __syncthreads();
    for (int base = 0; base < N; base += 4096) {
        const int i0 = base + tid*4;
        int a0=0,a1=0,a2=0,a3=0;
        if (i0 + 3 < N) { const int4 t = *(const int4*)(deg + i0); a0=t.x; a1=t.y; a2=t.z; a3=t.w; }
        else { if (i0 < N) a0=deg[i0]; if (i0+1 < N) a1=deg[i0+1]; if (i0+2 < N) a2=deg[i0+2]; }
        const int s1=a0+a1, s2=s1+a2, s3=s2+a3;
        int s = s3;
        #pragma unroll
        for (int d = 1; d < 64; d <<= 1) { const int t = __shfl_up(s, d); if (lane >= d) s += t; }
        if (lane == 63) wsumS[wid] = s;
        __syncthreads();
        const int c = carry;
        if (tid < 16) {
            int t = wsumS[tid];
            #pragma unroll
            for (int d = 1; d < 16; d <<= 1) { const int u = __shfl_up(t, d); if (tid >= d) t += u; }
            wsumS[tid] = t;
        }
        __syncthreads();
        const int ex = c + (wid ? wsumS[wid-1] : 0) + s - s3;
        if (i0 < N)     offsets[i0]   = ex;
        if (i0+1 < N)   offsets[i0+1] = ex + a0;
        if (i0+2 < N)   offsets[i0+2] = ex + s1;
        if (i0+3 < N)   offsets[i0+3] = ex + s2;
        __syncthreads();
        if (tid == 0) carry = c + wsumS[15];
        __syncthreads();
    }
    if (tid == 0) offsets[N] = carry;
}

__global__ __launch_bounds__(256) void k_fill(
    const int* __restrict__ edge, const int* __restrict__ nhop,
    const int* __restrict__ offsets, int* __restrict__ cursor, int* __restrict__ csr,
    int E1, int E2)
{
    const int E = E1+E2;
    const int e = blockIdx.x*256 + threadIdx.x;
    if (e >= E) return;
    const int src = (e < E1) ? edge[e] : nhop[e-E1];
    const int pos = atomicAdd(&cursor[src], 1);
    csr[offsets[src] + pos] = e;
}

// per-node wave gather over CSR; bf16 tables, u16x4 loads (8B/lane).
// lane layout: j=0..3 -> head h1=lane>>5, output o=4*(lane&31)+j; second slot head h1+2.
__global__ __launch_bounds__(256) void k4_gather(
    const int* __restrict__ edge, const int* __restrict__ nhop,
    const float* __restrict__ emb1, const float* __restrict__ emb2,
    const float* __restrict__ edge_e, const int* __restrict__ offsets, const int* __restrict__ csr,
    const u16* __restrict__ hsrc_bf, const u16* __restrict__ htgt_bf,
    const float* __restrict__ rowsum, const float* __restrict__ wsoft,
    float* __restrict__ pout, u16* __restrict__ semb_bf,
    int N, int E1, int E2)
{
    const int lane = threadIdx.x & 63;
    const int n = blockIdx.x*4 + (threadIdx.x >> 6);
    if (n >= N) return;
    const int h1 = lane >> 5;
    const float rsA = rowsum[(size_t)n*4 + h1];
    const float rsB = rowsum[(size_t)n*4 + h1 + 2];
    const u16* hs = hsrc_bf + (size_t)n*512;
    const u16x4 h4a = *(const u16x4*)(hs + lane*4);
    const u16x4 h4b = *(const u16x4*)(hs + 256 + lane*4);
    float accA[4], accB[4];
    #pragma unroll
    for (int j = 0; j < 4; ++j) { accA[j] = rsA*bf2f(h4a[j]); accB[j] = rsB*bf2f(h4b[j]); }
    float sm0=0.f, sm1=0.f, sm2=0.f, sm3=0.f;

    const int start = offsets[n], end = offsets[n+1];
    for (int cb = start; cb < end; cb += 64) {
        const int cnt = (end - cb < 64) ? (end - cb) : 64;
        int eL = 0, tgtL = 0;
        float eeL0=0.f, eeL1=0.f, eeL2=0.f, eeL3=0.f;
        if (cb + lane < end) {
            eL = csr[cb + lane];
            tgtL = (eL < E1) ? edge[E1 + eL] : nhop[E2 + (eL - E1)];
            const float4 t = *(const float4*)(edge_e + (size_t)eL*4);
            eeL0=t.x; eeL1=t.y; eeL2=t.z; eeL3=t.w;
        }
        for (int i = 0; i < cnt; ++i) {
            const int e   = __shfl(eL, i);
            const int tgt = __shfl(tgtL, i);
            const float e0 = __shfl(eeL0, i);
            const float e1 = __shfl(eeL1, i);
            const float e2 = __shfl(eeL2, i);
            const float e3 = __shfl(eeL3, i);
            const float* er = (e < E1) ? (emb1 + (size_t)e*64) : (emb2 + (size_t)(e-E1)*64);
            const float ev = er[lane];
            sm0 += e0*ev; sm1 += e1*ev; sm2 += e2*ev; sm3 += e3*ev;
            const u16* ht = htgt_bf + (size_t)tgt*512;
            const u16x4 t4a = *(const u16x4*)(ht + lane*4);
            const u16x4 t4b = *(const u16x4*)(ht + 256 + lane*4);
            const float eA = h1 ? e1 : e0;
            const float eB = h1 ? e3 : e2;
            #pragma unroll
            for (int j = 0; j < 4; ++j) {
                accA[j] += eA*bf2f(t4a[j]);
                accB[j] += eB*bf2f(t4b[j]);
            }
        }
    }
    const float w0=wsoft[0], w1=wsoft[1], w2=wsoft[2], w3=wsoft[3];
    // semb with wsoft folded, bf16
    u16* so = semb_bf + (size_t)n*256;
    so[lane]       = f2bf(w0*sm0);
    so[64 + lane]  = f2bf(w1*sm1);
    so[128 + lane] = f2bf(w2*sm2);
    so[192 + lane] = f2bf(w3*sm3);
    // head-combined pout
    const float wA = h1 ? w1 : w0;
    const float wB = h1 ? w3 : w2;
    float p[4];
    #pragma unroll
    for (int j = 0; j < 4; ++j) {
        p[j] = wA*accA[j] + wB*accB[j];
        p[j] += __shfl_xor(p[j], 32);
    }
    if (lane < 32) {
        float4 o4; o4.x=p[0]; o4.y=p[1]; o4.z=p[2]; o4.w=p[3];
        *(float4*)(pout + (size_t)n*128 + lane*4) = o4;
    }
}

// MFMA GEMM: out_add = semb_bf (N x 256) @ WcatT^T (256 x 128); fused epilogue.
__global__ __launch_bounds__(256) void k5_gemm(
    const u16* __restrict__ semb_bf, const u16* __restrict__ wcatT_bf,
    const float* __restrict__ rowsum, const float* __restrict__ orth_part,
    float* __restrict__ out, int N)
{
    __shared__ float DS[64*132];
    const int tid = threadIdx.x;
    if (blockIdx.x == 0 && tid == 0)
        out[(size_t)N*128] = 0.01f*(sqrtf(orth_part[0])+sqrtf(orth_part[1])+sqrtf(orth_part[2])+sqrtf(orth_part[3]));
    const int w = tid >> 6, lane = tid & 63;
    const int m = lane & 15, kg = lane >> 4;
    const int n0 = blockIdx.x*64;

    bf16x8 fa[8];
    {
        int row = n0 + w*16 + m; if (row >= N) row = N-1;
        const u16* ap = semb_bf + (size_t)row*256 + kg*8;
        #pragma unroll
        for (int ks = 0; ks < 8; ++ks) fa[ks] = *(const bf16x8*)(ap + ks*32);
    }
    f32x4 acc[8];
    #pragma unroll
    for (int nt = 0; nt < 8; ++nt) { acc[nt][0]=0.f; acc[nt][1]=0.f; acc[nt][2]=0.f; acc[nt][3]=0.f; }
    #pragma unroll
    for (int nt = 0; nt < 8; ++nt) {
        const u16* bp = wcatT_bf + (size_t)(nt*16 + m)*256 + kg*8;
        #pragma unroll
        for (int ks = 0; ks < 8; ++ks) {
            const bf16x8 fb = *(const bf16x8*)(bp + ks*32);
            acc[nt] = __builtin_amdgcn_mfma_f32_16x16x32_bf16(fa[ks], fb, acc[nt], 0, 0, 0);
        }
    }
    #pragma unroll
    for (int nt = 0; nt < 8; ++nt) {
        const int o = nt*16 + m;
        const int r0 = w*16 + kg*4;
        #pragma unroll
        for (int r = 0; r < 4; ++r)
            DS[(r0+r)*132 + o] = acc[nt][r];
    }
    __syncthreads();
    for (int idx = tid; idx < 2048; idx += 256) {
        const int row = idx >> 5, q = idx & 31;
        const int n = n0 + row;
        if (n < N) {
            const float4 d = *(const float4*)&DS[row*132 + q*4];
            float* op = out + (size_t)n*128 + q*4;
            const float4 pv = *(const float4*)op;
            const float rinv = 1.0f / fmaxf(rowsum[(size_t)n*4 + 3], 1e-12f);
            float v0 = (pv.x + d.x)*rinv;
            float v1 = (pv.y + d.y)*rinv;
            float v2 = (pv.z + d.z)*rinv;
            float v3 = (pv.w + d.w)*rinv;
            v0 = (v0 > 0.f) ? v0 : expm1f(v0);
            v1 = (v1 > 0.f) ? v1 : expm1f(v1);
            v2 = (v2 > 0.f) ? v2 : expm1f(v2);
            v3 = (v3 > 0.f) ? v3 : expm1f(v3);
            float4 r4; r4.x=v0; r4.y=v1; r4.z=v2; r4.w=v3;
            *(float4*)op = r4;
        }
    }
}

extern "C" void kernel_launch(void* const* d_in, const int* in_sizes, int n_in,
                              void* d_out, int out_size, void* d_ws, size_t ws_size,
                              hipStream_t stream)
{
    const float* input = (const float*)d_in[0];
    const int*   edge  = (const int*)d_in[1];
    const float* emb1  = (const float*)d_in[2];
    const int*   nhop  = (const int*)d_in[3];
    const float* emb2  = (const float*)d_in[4];
    const float* proj  = (const float*)d_in[5];
    const float* W     = (const float*)d_in[6];
    const float* a     = (const float*)d_in[7];
    const float* hw    = (const float*)d_in[8];
    float* out = (float*)d_out;

    const int N  = in_sizes[0] / 128;
    const int E1 = in_sizes[1] / 2;
    const int E2 = in_sizes[3] / 2;
    const int E  = E1 + E2;
    (void)n_in; (void)out_size; (void)ws_size;

    char* wsb = (char*)d_ws;
    size_t off = 0;
    auto alloc = [&](size_t bytes) -> char* {
        char* p = wsb + off;
        off += (bytes + 255) & ~(size_t)255;
        return p;
    };
    u16*   in_bf    = (u16*)alloc((size_t)N*128*2);
    u16*   hsrc_bf  = (u16*)alloc((size_t)N*512*2);
    u16*   htgt_bf  = (u16*)alloc((size_t)N*512*2);
    u16*   semb_bf  = (u16*)alloc((size_t)N*256*2);
    float* edge_e   = (float*)alloc((size_t)E*4*4);
    u16*   M_bf     = (u16*)alloc((size_t)8*16384*2);
    u16*   WcatT_bf = (u16*)alloc((size_t)128*256*2);
    float* asrc     = (float*)alloc(512*4);
    float* atgt     = (float*)alloc(512*4);
    float* arel     = (float*)alloc(256*4);
    float* s_src    = (float*)alloc((size_t)N*4*4);
    float* s_tgt    = (float*)alloc((size_t)N*4*4);
    float* wsoft    = (float*)alloc(4*4);
    float* rowsum   = (float*)alloc((size_t)N*4*4);
    float* orth_part= (float*)alloc(4*4);
    int* deg        = (int*)alloc((size_t)N*4);
    int* cursor     = (int*)alloc((size_t)N*4);
    int* offsets    = (int*)alloc((size_t)(N+1)*4);
    int* csr        = (int*)alloc((size_t)E*4);

    hipMemsetAsync(rowsum, 0, (size_t)N*4*4, stream);
    hipMemsetAsync(orth_part, 0, 4*4, stream);
    hipMemsetAsync(deg, 0, (size_t)N*4, stream);
    hipMemsetAsync(cursor, 0, (size_t)N*4, stream);

    kc_bf16<<<dim3((N*128/8 + 255)/256), dim3(256), 0, stream>>>(input, in_bf, N*128/8);
    k1_prep<<<dim3(NHEAD,3,4), dim3(256), 0, stream>>>(proj, W, a, hw, M_bf,
                                                       asrc, atgt, arel, WcatT_bf, wsoft, orth_part);
    k2_mfma<<<dim3((N+63)/64), dim3(256), 0, stream>>>(in_bf, M_bf, hsrc_bf, htgt_bf, N);
    k2b_scores<<<dim3((N+255)/256), dim3(256), 0, stream>>>(input, asrc, atgt, s_src, s_tgt, N);
    k3_edges<<<dim3((E+255)/256), dim3(256), 0, stream>>>(edge, nhop, emb1, emb2, s_src, s_tgt,
                                                          arel, edge_e, rowsum, deg, E1, E2);
    k_scan<<<dim3(1), dim3(1024), 0, stream>>>(deg, offsets, N);
    k_fill<<<dim3((E+255)/256), dim3(256), 0, stream>>>(edge, nhop, offsets, cursor, csr, E1, E2);
    k4_gather<<<dim3((N+3)/4), dim3(256), 0, stream>>>(edge, nhop, emb1, emb2, edge_e, offsets, csr,
                                                       hsrc_bf, htgt_bf, rowsum, wsoft,
                                                       out, semb_bf, N, E1, E2);
    k5_gemm<<<dim3((N+63)/64), dim3(256), 0, stream>>>(semb_bf, WcatT_bf, rowsum, orth_part,
                                                       out, N);
}

// Round 3
// 388.166 us; speedup vs baseline: 2.6436x; 1.0619x over previous
//
#include <hip/hip_runtime.h>
#include <math.h>

// SpGraphAttentionLayer on MI355X — round 3.
// k2 split across (node-tile, matrix) grid for occupancy; k4 gather pipelined with
// coalesced CSR-ordered metadata (csr_tgt, ee_perm) and bf16 emb; 3-kernel scan.

#define NHEAD 4

typedef unsigned short u16;
typedef __attribute__((ext_vector_type(4))) unsigned short u16x4;
typedef __attribute__((ext_vector_type(8))) unsigned short u16x8;
typedef __attribute__((ext_vector_type(8))) short bf16x8;
typedef __attribute__((ext_vector_type(4))) float f32x4;

__device__ __forceinline__ float bf2f(u16 v) {
    union { unsigned u; float f; } x; x.u = ((unsigned)v) << 16; return x.f;
}
__device__ __forceinline__ u16 f2bf(float f) {
    union { float f; unsigned u; } x; x.f = f;
    const unsigned r = x.u + 0x7FFFu + ((x.u >> 16) & 1u);
    return (u16)(r >> 16);
}

// input fp32 -> bf16
__global__ __launch_bounds__(256) void kc_bf16(const float* __restrict__ in, u16* __restrict__ out, int total8)
{
    const int i = blockIdx.x*256 + threadIdx.x;
    if (i >= total8) return;
    const float4* p = (const float4*)(in + (size_t)i*8);
    const float4 a = p[0], b = p[1];
    u16 v[8];
    v[0]=f2bf(a.x); v[1]=f2bf(a.y); v[2]=f2bf(a.z); v[3]=f2bf(a.w);
    v[4]=f2bf(b.x); v[5]=f2bf(b.y); v[6]=f2bf(b.z); v[7]=f2bf(b.w);
    *(bf16x8*)(out + (size_t)i*8) = *(bf16x8*)v;
}

__global__ __launch_bounds__(256) void k1_prep(
    const float* __restrict__ proj, const float* __restrict__ W,
    const float* __restrict__ a, const float* __restrict__ hw,
    u16* __restrict__ M_bf,
    float* __restrict__ asrc, float* __restrict__ atgt, float* __restrict__ arel,
    u16* __restrict__ WcatT_bf, float* __restrict__ wsoft,
    float* __restrict__ orth_part)
{
    __shared__ float projS[128*132];
    __shared__ float WS[32*132];
    __shared__ float tS[128];
    __shared__ float red[256];
    const int h = blockIdx.x;
    const int part = blockIdx.y;
    const int z = blockIdx.z;
    const int tid = threadIdx.x;
    const float* projH = proj + h*(128*128);
    const float* WH = W + h*(128*320);
    const float* aH = a + h*128;

    {
        const float4* p4 = (const float4*)projH;
        for (int idx = tid; idx < 4096; idx += 256)
            *(float4*)&projS[(idx>>5)*132 + (idx&31)*4] = p4[idx];
    }

    if (part < 2) {
        const int koff = part ? 128 : 0;
        for (int idx = tid; idx < 1024; idx += 256) {
            const int ol = idx>>5, jq = idx&31;
            *(float4*)&WS[ol*132 + jq*4] = *(const float4*)&WH[(z*32+ol)*320 + koff + jq*4];
        }
        __syncthreads();
        u16* Mout = M_bf + ((size_t)(part*4 + h))*16384;
        for (int idx = tid; idx < 1024; idx += 256) {
            const int ol = idx>>5, jq = idx&31;
            float4 acc; acc.x=0.f; acc.y=0.f; acc.z=0.f; acc.w=0.f;
            for (int i = 0; i < 128; ++i) {
                const float wv = WS[ol*132 + i];
                const float4 pv = *(const float4*)&projS[i*132 + jq*4];
                acc.x += wv*pv.x; acc.y += wv*pv.y; acc.z += wv*pv.z; acc.w += wv*pv.w;
            }
            u16x4 pk; pk.x=f2bf(acc.x); pk.y=f2bf(acc.y); pk.z=f2bf(acc.z); pk.w=f2bf(acc.w);
            *(u16x4*)&Mout[(z*32+ol)*128 + jq*4] = pk;
        }
        if (z == 0) {
            if (tid < 128) {
                float s = 0.f;
                for (int o = 0; o < 128; ++o) s += aH[o]*WH[o*320 + koff + tid];
                tS[tid] = s;
            }
            __syncthreads();
            if (tid < 128) {
                float s = 0.f;
                for (int i = 0; i < 128; ++i) s += tS[i]*projS[i*132 + tid];
                (part ? atgt : asrc)[h*128 + tid] = s;
            }
        }
    } else {
        __syncthreads();
        float local = 0.f;
        const int base = z*4096;
        for (int idx = base + tid; idx < base + 4096; idx += 256) {
            const int i = idx>>7, k = idx&127;
            float s = 0.f;
            for (int q = 0; q < 32; ++q) {
                const float4 pi = *(const float4*)&projS[i*132 + q*4];
                const float4 pk = *(const float4*)&projS[k*132 + q*4];
                s += pi.x*pk.x + pi.y*pk.y + pi.z*pk.z + pi.w*pk.w;
            }
            if (i == k) s -= 1.f;
            local += s*s;
        }
        red[tid] = local;
        __syncthreads();
        for (int st = 128; st > 0; st >>= 1) {
            if (tid < st) red[tid] += red[tid+st];
            __syncthreads();
        }
        if (tid == 0) atomicAdd(&orth_part[h], red[0]);
        if (z == 0) {
            if (tid < 64) {
                float s = 0.f;
                for (int o = 0; o < 128; ++o) s += aH[o]*WH[o*320 + 256 + tid];
                arel[h*64 + tid] = s;
            }
            for (int idx = tid; idx < 8192; idx += 256) {
                const int r = idx & 63, o = idx >> 6;
                WcatT_bf[(size_t)o*256 + h*64 + r] = f2bf(WH[o*320 + 256 + r]);
            }
            if (h == 0 && tid == 0) {
                const float m = fmaxf(fmaxf(hw[0],hw[1]), fmaxf(hw[2],hw[3]));
                const float e0=expf(hw[0]-m), e1=expf(hw[1]-m), e2=expf(hw[2]-m), e3=expf(hw[3]-m);
                const float s = e0+e1+e2+e3;
                wsoft[0]=e0/s; wsoft[1]=e1/s; wsoft[2]=e2/s; wsoft[3]=e3/s;
            }
        }
    }
}

// MFMA bf16 node-table GEMM: 64 nodes x one matrix per block (grid.y = mat 0..7).
__global__ __launch_bounds__(256) void k2_mfma(
    const u16* __restrict__ in_bf, const u16* __restrict__ M_bf,
    u16* __restrict__ hsrc_bf, u16* __restrict__ htgt_bf, int N)
{
    __shared__ u16 DS[64*136];
    const int tid = threadIdx.x;
    const int w = tid >> 6, lane = tid & 63;
    const int n0 = blockIdx.x*64;
    const int mat = blockIdx.y;
    const int m = lane & 15, kg = lane >> 4;

    bf16x8 fa[4];
    {
        int row = n0 + w*16 + m; if (row >= N) row = N-1;
        const u16* ap = in_bf + (size_t)row*128 + kg*8;
        #pragma unroll
        for (int ks = 0; ks < 4; ++ks) fa[ks] = *(const bf16x8*)(ap + ks*32);
    }

    const u16* Mp = M_bf + (size_t)mat*16384;
    f32x4 acc[8];
    #pragma unroll
    for (int nt = 0; nt < 8; ++nt) { acc[nt][0]=0.f; acc[nt][1]=0.f; acc[nt][2]=0.f; acc[nt][3]=0.f; }
    #pragma unroll
    for (int nt = 0; nt < 8; ++nt) {
        const u16* bp = Mp + (size_t)(nt*16 + m)*128 + kg*8;
        #pragma unroll
        for (int ks = 0; ks < 4; ++ks) {
            const bf16x8 fb = *(const bf16x8*)(bp + ks*32);
            acc[nt] = __builtin_amdgcn_mfma_f32_16x16x32_bf16(fa[ks], fb, acc[nt], 0, 0, 0);
        }
    }
    #pragma unroll
    for (int nt = 0; nt < 8; ++nt) {
        const int o = nt*16 + m;
        const int r0 = w*16 + kg*4;
        #pragma unroll
        for (int r = 0; r < 4; ++r)
            DS[(r0+r)*136 + o] = f2bf(acc[nt][r]);
    }
    __syncthreads();
    const int p = mat >> 2, hh = mat & 3;
    u16* outT = p ? htgt_bf : hsrc_bf;
    for (int idx = tid; idx < 1024; idx += 256) {
        const int row = idx >> 4, seg = idx & 15;
        const int n = n0 + row;
        if (n < N) {
            const bf16x8 v = *(const bf16x8*)&DS[row*136 + seg*8];
            *(bf16x8*)(outT + (size_t)n*512 + hh*128 + seg*8) = v;
        }
    }
}

__global__ __launch_bounds__(256) void k2b_scores(
    const float* __restrict__ input, const float* __restrict__ asrc, const float* __restrict__ atgt,
    float* __restrict__ s_src, float* __restrict__ s_tgt, int N)
{
    __shared__ float aS[512], tS[512];
    const int tid = threadIdx.x;
    for (int idx = tid; idx < 512; idx += 256) { aS[idx] = asrc[idx]; tS[idx] = atgt[idx]; }
    __syncthreads();
    const int n = blockIdx.x*256 + tid;
    if (n >= N) return;
    const float4* inr = (const float4*)(input + (size_t)n*128);
    float ss[4] = {0.f,0.f,0.f,0.f}, st[4] = {0.f,0.f,0.f,0.f};
    for (int q = 0; q < 32; ++q) {
        const float4 v = inr[q];
        #pragma unroll
        for (int hh = 0; hh < 4; ++hh) {
            const float4 av = *(const float4*)&aS[hh*128 + q*4];
            const float4 tv = *(const float4*)&tS[hh*128 + q*4];
            ss[hh] += v.x*av.x + v.y*av.y + v.z*av.z + v.w*av.w;
            st[hh] += v.x*tv.x + v.y*tv.y + v.z*tv.z + v.w*tv.w;
        }
    }
    float4 o1; o1.x=ss[0]; o1.y=ss[1]; o1.z=ss[2]; o1.w=ss[3];
    float4 o2; o2.x=st[0]; o2.y=st[1]; o2.z=st[2]; o2.w=st[3];
    *(float4*)(s_src + (size_t)n*4) = o1;
    *(float4*)(s_tgt + (size_t)n*4) = o2;
}

// per-edge: scores (fp32), edge_e, rowsum atomics, deg histogram, emb -> bf16
__global__ __launch_bounds__(256) void k3_edges(
    const int* __restrict__ edge, const int* __restrict__ nhop,
    const float* __restrict__ emb1, const float* __restrict__ emb2,
    const float* __restrict__ s_src, const float* __restrict__ s_tgt,
    const float* __restrict__ arel,
    float* __restrict__ edge_e, float* __restrict__ rowsum, int* __restrict__ deg,
    u16* __restrict__ emb_bf,
    int E1, int E2)
{
    __shared__ float arelS[256];
    const int tid = threadIdx.x;
    arelS[tid] = arel[tid];
    __syncthreads();
    const int E = E1 + E2;
    const int e = blockIdx.x*256 + tid;
    if (e >= E) return;
    int src, tgt; const float* er;
    if (e < E1) { src = edge[e]; tgt = edge[E1+e]; er = emb1 + (size_t)e*64; }
    else { const int e2 = e-E1; src = nhop[e2]; tgt = nhop[E2+e2]; er = emb2 + (size_t)e2*64; }
    float sr[4] = {0.f,0.f,0.f,0.f};
    const float4* er4 = (const float4*)er;
    u16* eb = emb_bf + (size_t)e*64;
    for (int q = 0; q < 16; ++q) {
        const float4 v = er4[q];
        u16x4 pk; pk.x=f2bf(v.x); pk.y=f2bf(v.y); pk.z=f2bf(v.z); pk.w=f2bf(v.w);
        *(u16x4*)(eb + q*4) = pk;
        #pragma unroll
        for (int hh = 0; hh < 4; ++hh) {
            const float4 av = *(const float4*)&arelS[hh*64 + q*4];
            sr[hh] += v.x*av.x + v.y*av.y + v.z*av.z + v.w*av.w;
        }
    }
    const float4 s4 = *(const float4*)(s_src + (size_t)src*4);
    const float4 t4 = *(const float4*)(s_tgt + (size_t)tgt*4);
    const float sv[4] = {s4.x,s4.y,s4.z,s4.w};
    const float tv[4] = {t4.x,t4.y,t4.z,t4.w};
    float ee[4];
    #pragma unroll
    for (int hh = 0; hh < 4; ++hh) {
        const float sc = sv[hh] + tv[hh] + sr[hh];
        const float p = (sc > 0.f) ? -sc : (-0.2f*sc);
        ee[hh] = expf(p);
        atomicAdd(&rowsum[(size_t)src*4 + hh], ee[hh]);
    }
    float4 eo; eo.x=ee[0]; eo.y=ee[1]; eo.z=ee[2]; eo.w=ee[3];
    *(float4*)(edge_e + (size_t)e*4) = eo;
    atomicAdd(&deg[src], 1);
}

// 3-kernel scan: per-block partial scan -> block-sum scan -> add pass
__global__ __launch_bounds__(1024) void k_scanA(const int* __restrict__ deg, int* __restrict__ offsets,
                                                int* __restrict__ bsum, int N)
{
    __shared__ int wsumS[16];
    const int tid = threadIdx.x;
    const int lane = tid & 63, wid = tid >> 6;
    const int i0 = blockIdx.x*4096 + tid*4;
    int a0=0,a1=0,a2=0,a3=0;
    if (i0 + 3 < N) { const int4 t = *(const int4*)(deg + i0); a0=t.x; a1=t.y; a2=t.z; a3=t.w; }
    else { if (i0 < N) a0=deg[i0]; if (i0+1 < N) a1=deg[i0+1]; if (i0+2 < N) a2=deg[i0+2]; }
    const int s1=a0+a1, s2=s1+a2, s3=s2+a3;
    int s = s3;
    #pragma unroll
    for (int d = 1; d < 64; d <<= 1) { const int t = __shfl_up(s, d); if (lane >= d) s += t; }
    if (lane == 63) wsumS[wid] = s;
    __syncthreads();
    if (tid < 16) {
        int t = wsumS[tid];
        #pragma unroll
        for (int d = 1; d < 16; d <<= 1) { const int u = __shfl_up(t, d); if (tid >= d) t += u; }
        wsumS[tid] = t;
    }
    __syncthreads();
    const int ex = (wid ? wsumS[wid-1] : 0) + s - s3;
    if (i0 < N)     offsets[i0]   = ex;
    if (i0+1 < N)   offsets[i0+1] = ex + a0;
    if (i0+2 < N)   offsets[i0+2] = ex + s1;
    if (i0+3 < N)   offsets[i0+3] = ex + s2;
    if (tid == 0) bsum[blockIdx.x] = wsumS[15];
}

__global__ __launch_bounds__(64) void k_scanB(const int* __restrict__ bsum, int* __restrict__ boff,
                                              int* __restrict__ offsets, int nb, int N)
{
    const int tid = threadIdx.x;
    const int v = (tid < nb) ? bsum[tid] : 0;
    int s = v;
    #pragma unroll
    for (int d = 1; d < 64; d <<= 1) { const int t = __shfl_up(s, d); if (tid >= d) s += t; }
    if (tid < nb) boff[tid] = s - v;
    if (tid == 63) offsets[N] = s;
}

__global__ __launch_bounds__(256) void k_scanC(int* __restrict__ offsets, const int* __restrict__ boff, int N)
{
    const int i = blockIdx.x*256 + threadIdx.x;
    if (i < N) offsets[i] += boff[i >> 12];
}

// counting-sort fill: CSR-ordered edge id, tgt, and permuted edge_e
__global__ __launch_bounds__(256) void k_fill(
    const int* __restrict__ edge, const int* __restrict__ nhop,
    const float* __restrict__ edge_e,
    const int* __restrict__ offsets, int* __restrict__ cursor,
    int* __restrict__ csr_e, int* __restrict__ csr_tgt, float* __restrict__ ee_perm,
    int E1, int E2)
{
    const int E = E1+E2;
    const int e = blockIdx.x*256 + threadIdx.x;
    if (e >= E) return;
    int src, tgt;
    if (e < E1) { src = edge[e]; tgt = edge[E1+e]; }
    else { const int e2 = e-E1; src = nhop[e2]; tgt = nhop[E2+e2]; }
    const int pos = atomicAdd(&cursor[src], 1);
    const int p = offsets[src] + pos;
    csr_e[p] = e;
    csr_tgt[p] = tgt;
    *(float4*)(ee_perm + (size_t)p*4) = *(const float4*)(edge_e + (size_t)e*4);
}

// per-node wave gather. lane l: head hl=l>>4, dims ob=(l&15)*8 .. +7 (one u16x8 = 16B/lane).
// heads combined at the end via shfl_xor(16,32). Inner loop software-pipelined.
__global__ __launch_bounds__(256) void k4_gather(
    const float* __restrict__ ee_perm, const int* __restrict__ offsets,
    const int* __restrict__ csr_e, const int* __restrict__ csr_tgt,
    const u16* __restrict__ emb_bf,
    const u16* __restrict__ hsrc_bf, const u16* __restrict__ htgt_bf,
    const float* __restrict__ rowsum, const float* __restrict__ wsoft,
    float* __restrict__ pout, u16* __restrict__ semb_bf,
    int N)
{
    const int lane = threadIdx.x & 63;
    const int n = blockIdx.x*4 + (threadIdx.x >> 6);
    if (n >= N) return;
    const int hl = lane >> 4;
    const int hoff = hl*128 + (lane & 15)*8;

    union HT { u16x8 v; unsigned u[4]; };

    const float4 rs4 = *(const float4*)(rowsum + (size_t)n*4);
    const float rsh = (hl==0)?rs4.x:(hl==1)?rs4.y:(hl==2)?rs4.z:rs4.w;
    float acc[8];
    {
        HT hs; hs.v = *(const u16x8*)(hsrc_bf + (size_t)n*512 + hoff);
        #pragma unroll
        for (int p = 0; p < 4; ++p) {
            union{unsigned u; float f;} lo, hi;
            lo.u = hs.u[p] << 16; hi.u = hs.u[p] & 0xffff0000u;
            acc[2*p]   = rsh*lo.f;
            acc[2*p+1] = rsh*hi.f;
        }
    }
    float sm0=0.f, sm1=0.f, sm2=0.f, sm3=0.f;

    const int start = offsets[n], end = offsets[n+1];
    for (int cb = start; cb < end; cb += 64) {
        const int cnt = (end - cb < 64) ? (end - cb) : 64;
        int eL = 0, tgtL = 0;
        float4 eeL; eeL.x=0.f; eeL.y=0.f; eeL.z=0.f; eeL.w=0.f;
        if (cb + lane < end) {
            eL   = csr_e[cb + lane];
            tgtL = csr_tgt[cb + lane];
            eeL  = *(const float4*)(ee_perm + (size_t)(cb + lane)*4);
        }
        int tgt_c = __shfl(tgtL, 0), e_c = __shfl(eL, 0);
        HT ht; ht.v = *(const u16x8*)(htgt_bf + (size_t)tgt_c*512 + hoff);
        u16 em = emb_bf[(size_t)e_c*64 + lane];
        for (int i = 0; i < cnt; ++i) {
            const float e0 = __shfl(eeL.x, i);
            const float e1 = __shfl(eeL.y, i);
            const float e2 = __shfl(eeL.z, i);
            const float e3 = __shfl(eeL.w, i);
            const int ip = (i+1 < cnt) ? (i+1) : i;
            const int tgt_n = __shfl(tgtL, ip);
            const int e_n   = __shfl(eL, ip);
            HT htn; htn.v = *(const u16x8*)(htgt_bf + (size_t)tgt_n*512 + hoff);
            const u16 emn = emb_bf[(size_t)e_n*64 + lane];
            const float eh = (hl==0)?e0:(hl==1)?e1:(hl==2)?e2:e3;
            #pragma unroll
            for (int p = 0; p < 4; ++p) {
                union{unsigned u; float f;} lo, hi;
                lo.u = ht.u[p] << 16; hi.u = ht.u[p] & 0xffff0000u;
                acc[2*p]   += eh*lo.f;
                acc[2*p+1] += eh*hi.f;
            }
            const float ev = bf2f(em);
            sm0 += e0*ev; sm1 += e1*ev; sm2 += e2*ev; sm3 += e3*ev;
            ht = htn; em = emn;
        }
    }
    const float4 ws4 = *(const float4*)wsoft;
    const float wh = (hl==0)?ws4.x:(hl==1)?ws4.y:(hl==2)?ws4.z:ws4.w;
    float p[8];
    #pragma unroll
    for (int j = 0; j < 8; ++j) {
        float pv = wh*acc[j];
        pv += __shfl_xor(pv, 16);
        pv += __shfl_xor(pv, 32);
        p[j] = pv;
    }
    if (hl == 0) {
        float* op = pout + (size_t)n*128 + (lane & 15)*8;
        float4 A; A.x=p[0]; A.y=p[1]; A.z=p[2]; A.w=p[3];
        float4 B; B.x=p[4]; B.y=p[5]; B.z=p[6]; B.w=p[7];
        *(float4*)op = A;
        *(float4*)(op+4) = B;
    }
    u16* so = semb_bf + (size_t)n*256;
    so[lane]       = f2bf(ws4.x*sm0);
    so[64 + lane]  = f2bf(ws4.y*sm1);
    so[128 + lane] = f2bf(ws4.z*sm2);
    so[192 + lane] = f2bf(ws4.w*sm3);
}

// MFMA GEMM: out_add = semb_bf (N x 256) @ WcatT^T (256 x 128); fused epilogue.
__global__ __launch_bounds__(256) void k5_gemm(
    const u16* __restrict__ semb_bf, const u16* __restrict__ wcatT_bf,
    const float* __restrict__ rowsum, const float* __restrict__ orth_part,
    float* __restrict__ out, int N)
{
    __shared__ float DS[64*132];
    const int tid = threadIdx.x;
    if (blockIdx.x == 0 && tid == 0)
        out[(size_t)N*128] = 0.01f*(sqrtf(orth_part[0])+sqrtf(orth_part[1])+sqrtf(orth_part[2])+sqrtf(orth_part[3]));
    const int w = tid >> 6, lane = tid & 63;
    const int m = lane & 15, kg = lane >> 4;
    const int n0 = blockIdx.x*64;

    bf16x8 fa[8];
    {
        int row = n0 + w*16 + m; if (row >= N) row = N-1;
        const u16* ap = semb_bf + (size_t)row*256 + kg*8;
        #pragma unroll
        for (int ks = 0; ks < 8; ++ks) fa[ks] = *(const bf16x8*)(ap + ks*32);
    }
    f32x4 acc[8];
    #pragma unroll
    for (int nt = 0; nt < 8; ++nt) { acc[nt][0]=0.f; acc[nt][1]=0.f; acc[nt][2]=0.f; acc[nt][3]=0.f; }
    #pragma unroll
    for (int nt = 0; nt < 8; ++nt) {
        const u16* bp = wcatT_bf + (size_t)(nt*16 + m)*256 + kg*8;
        #pragma unroll
        for (int ks = 0; ks < 8; ++ks) {
            const bf16x8 fb = *(const bf16x8*)(bp + ks*32);
            acc[nt] = __builtin_amdgcn_mfma_f32_16x16x32_bf16(fa[ks], fb, acc[nt], 0, 0, 0);
        }
    }
    #pragma unroll
    for (int nt = 0; nt < 8; ++nt) {
        const int o = nt*16 + m;
        const int r0 = w*16 + kg*4;
        #pragma unroll
        for (int r = 0; r < 4; ++r)
            DS[(r0+r)*132 + o] = acc[nt][r];
    }
    __syncthreads();
    for (int idx = tid; idx < 2048; idx += 256) {
        const int row = idx >> 5, q = idx & 31;
        const int n = n0 + row;
        if (n < N) {
            const float4 d = *(const float4*)&DS[row*132 + q*4];
            float* op = out + (size_t)n*128 + q*4;
            const float4 pv = *(const float4*)op;
            const float rinv = 1.0f / fmaxf(rowsum[(size_t)n*4 + 3], 1e-12f);
            float v0 = (pv.x + d.x)*rinv;
            float v1 = (pv.y + d.y)*rinv;
            float v2 = (pv.z + d.z)*rinv;
            float v3 = (pv.w + d.w)*rinv;
            v0 = (v0 > 0.f) ? v0 : expm1f(v0);
            v1 = (v1 > 0.f) ? v1 : expm1f(v1);
            v2 = (v2 > 0.f) ? v2 : expm1f(v2);
            v3 = (v3 > 0.f) ? v3 : expm1f(v3);
            float4 r4; r4.x=v0; r4.y=v1; r4.z=v2; r4.w=v3;
            *(float4*)op = r4;
        }
    }
}

extern "C" void kernel_launch(void* const* d_in, const int* in_sizes, int n_in,
                              void* d_out, int out_size, void* d_ws, size_t ws_size,
                              hipStream_t stream)
{
    const float* input = (const float*)d_in[0];
    const int*   edge  = (const int*)d_in[1];
    const float* emb1  = (const float*)d_in[2];
    const int*   nhop  = (const int*)d_in[3];
    const float* emb2  = (const float*)d_in[4];
    const float* proj  = (const float*)d_in[5];
    const float* W     = (const float*)d_in[6];
    const float* a     = (const float*)d_in[7];
    const float* hw    = (const float*)d_in[8];
    float* out = (float*)d_out;

    const int N  = in_sizes[0] / 128;
    const int E1 = in_sizes[1] / 2;
    const int E2 = in_sizes[3] / 2;
    const int E  = E1 + E2;
    (void)n_in; (void)out_size; (void)ws_size;

    char* wsb = (char*)d_ws;
    size_t off = 0;
    auto alloc = [&](size_t bytes) -> char* {
        char* p = wsb + off;
        off += (bytes + 255) & ~(size_t)255;
        return p;
    };
    u16*   in_bf    = (u16*)alloc((size_t)N*128*2);
    u16*   hsrc_bf  = (u16*)alloc((size_t)N*512*2);
    u16*   htgt_bf  = (u16*)alloc((size_t)N*512*2);
    u16*   semb_bf  = (u16*)alloc((size_t)N*256*2);
    u16*   emb_bf   = (u16*)alloc((size_t)E*64*2);
    float* edge_e   = (float*)alloc((size_t)E*4*4);
    float* ee_perm  = (float*)alloc((size_t)E*4*4);
    int*   csr_e    = (int*)alloc((size_t)E*4);
    int*   csr_tgt  = (int*)alloc((size_t)E*4);
    u16*   M_bf     = (u16*)alloc((size_t)8*16384*2);
    u16*   WcatT_bf = (u16*)alloc((size_t)128*256*2);
    float* asrc     = (float*)alloc(512*4);
    float* atgt     = (float*)alloc(512*4);
    float* arel     = (float*)alloc(256*4);
    float* s_src    = (float*)alloc((size_t)N*4*4);
    float* s_tgt    = (float*)alloc((size_t)N*4*4);
    float* wsoft    = (float*)alloc(4*4);
    int*   offsets  = (int*)alloc((size_t)(N+1)*4);
    int*   bsum     = (int*)alloc(64*4);
    int*   boff     = (int*)alloc(64*4);
    // zero region: rowsum, orth_part, deg, cursor (one memset)
    const size_t zoff0 = off;
    float* rowsum   = (float*)alloc((size_t)N*4*4);
    float* orth_part= (float*)alloc(4*4);
    int*   deg      = (int*)alloc((size_t)N*4);
    int*   cursor   = (int*)alloc((size_t)N*4);
    const size_t zoff1 = off;

    hipMemsetAsync(wsb + zoff0, 0, zoff1 - zoff0, stream);

    const int nbScan = (N + 4095) / 4096;

    kc_bf16<<<dim3((N*128/8 + 255)/256), dim3(256), 0, stream>>>(input, in_bf, N*128/8);
    k1_prep<<<dim3(NHEAD,3,4), dim3(256), 0, stream>>>(proj, W, a, hw, M_bf,
                                                       asrc, atgt, arel, WcatT_bf, wsoft, orth_part);
    k2_mfma<<<dim3((N+63)/64, 8), dim3(256), 0, stream>>>(in_bf, M_bf, hsrc_bf, htgt_bf, N);
    k2b_scores<<<dim3((N+255)/256), dim3(256), 0, stream>>>(input, asrc, atgt, s_src, s_tgt, N);
    k3_edges<<<dim3((E+255)/256), dim3(256), 0, stream>>>(edge, nhop, emb1, emb2, s_src, s_tgt,
                                                          arel, edge_e, rowsum, deg, emb_bf, E1, E2);
    k_scanA<<<dim3(nbScan), dim3(1024), 0, stream>>>(deg, offsets, bsum, N);
    k_scanB<<<dim3(1), dim3(64), 0, stream>>>(bsum, boff, offsets, nbScan, N);
    k_scanC<<<dim3((N+255)/256), dim3(256), 0, stream>>>(offsets, boff, N);
    k_fill<<<dim3((E+255)/256), dim3(256), 0, stream>>>(edge, nhop, edge_e, offsets, cursor,
                                                        csr_e, csr_tgt, ee_perm, E1, E2);
    k4_gather<<<dim3((N+3)/4), dim3(256), 0, stream>>>(ee_perm, offsets, csr_e, csr_tgt, emb_bf,
                                                       hsrc_bf, htgt_bf, rowsum, wsoft,
                                                       out, semb_bf, N);
    k5_gemm<<<dim3((N+63)/64), dim3(256), 0, stream>>>(semb_bf, WcatT_bf, rowsum, orth_part,
                                                       out, N);
}

// Round 4
// 322.006 us; speedup vs baseline: 3.1867x; 1.2055x over previous
//
#include <hip/hip_runtime.h>
#include <math.h>

// SpGraphAttentionLayer on MI355X — round 4.
// k2 restructured as canonical LDS-tiled MFMA GEMM: 256 nodes x 128 cols per block,
// M staged in LDS with XOR swizzle (T2), A-fragments in registers, D repacked via LDS.
// Node tables merged into tbl[n][1024] (src heads 0..511, tgt heads 512..1023).

#define NHEAD 4

typedef unsigned short u16;
typedef __attribute__((ext_vector_type(4))) unsigned short u16x4;
typedef __attribute__((ext_vector_type(8))) unsigned short u16x8;
typedef __attribute__((ext_vector_type(8))) short bf16x8;
typedef __attribute__((ext_vector_type(4))) float f32x4;

__device__ __forceinline__ float bf2f(u16 v) {
    union { unsigned u; float f; } x; x.u = ((unsigned)v) << 16; return x.f;
}
__device__ __forceinline__ u16 f2bf(float f) {
    union { float f; unsigned u; } x; x.f = f;
    const unsigned r = x.u + 0x7FFFu + ((x.u >> 16) & 1u);
    return (u16)(r >> 16);
}

// input fp32 -> bf16
__global__ __launch_bounds__(256) void kc_bf16(const float* __restrict__ in, u16* __restrict__ out, int total8)
{
    const int i = blockIdx.x*256 + threadIdx.x;
    if (i >= total8) return;
    const float4* p = (const float4*)(in + (size_t)i*8);
    const float4 a = p[0], b = p[1];
    u16 v[8];
    v[0]=f2bf(a.x); v[1]=f2bf(a.y); v[2]=f2bf(a.z); v[3]=f2bf(a.w);
    v[4]=f2bf(b.x); v[5]=f2bf(b.y); v[6]=f2bf(b.z); v[7]=f2bf(b.w);
    *(bf16x8*)(out + (size_t)i*8) = *(bf16x8*)v;
}

__global__ __launch_bounds__(256) void k1_prep(
    const float* __restrict__ proj, const float* __restrict__ W,
    const float* __restrict__ a, const float* __restrict__ hw,
    u16* __restrict__ M_bf,
    float* __restrict__ asrc, float* __restrict__ atgt, float* __restrict__ arel,
    u16* __restrict__ WcatT_bf, float* __restrict__ wsoft,
    float* __restrict__ orth_part)
{
    __shared__ float projS[128*132];
    __shared__ float WS[32*132];
    __shared__ float tS[128];
    __shared__ float red[256];
    const int h = blockIdx.x;
    const int part = blockIdx.y;
    const int z = blockIdx.z;
    const int tid = threadIdx.x;
    const float* projH = proj + h*(128*128);
    const float* WH = W + h*(128*320);
    const float* aH = a + h*128;

    {
        const float4* p4 = (const float4*)projH;
        for (int idx = tid; idx < 4096; idx += 256)
            *(float4*)&projS[(idx>>5)*132 + (idx&31)*4] = p4[idx];
    }

    if (part < 2) {
        const int koff = part ? 128 : 0;
        for (int idx = tid; idx < 1024; idx += 256) {
            const int ol = idx>>5, jq = idx&31;
            *(float4*)&WS[ol*132 + jq*4] = *(const float4*)&WH[(z*32+ol)*320 + koff + jq*4];
        }
        __syncthreads();
        u16* Mout = M_bf + ((size_t)(part*4 + h))*16384;
        for (int idx = tid; idx < 1024; idx += 256) {
            const int ol = idx>>5, jq = idx&31;
            float4 acc; acc.x=0.f; acc.y=0.f; acc.z=0.f; acc.w=0.f;
            for (int i = 0; i < 128; ++i) {
                const float wv = WS[ol*132 + i];
                const float4 pv = *(const float4*)&projS[i*132 + jq*4];
                acc.x += wv*pv.x; acc.y += wv*pv.y; acc.z += wv*pv.z; acc.w += wv*pv.w;
            }
            u16x4 pk; pk.x=f2bf(acc.x); pk.y=f2bf(acc.y); pk.z=f2bf(acc.z); pk.w=f2bf(acc.w);
            *(u16x4*)&Mout[(z*32+ol)*128 + jq*4] = pk;
        }
        if (z == 0) {
            if (tid < 128) {
                float s = 0.f;
                for (int o = 0; o < 128; ++o) s += aH[o]*WH[o*320 + koff + tid];
                tS[tid] = s;
            }
            __syncthreads();
            if (tid < 128) {
                float s = 0.f;
                for (int i = 0; i < 128; ++i) s += tS[i]*projS[i*132 + tid];
                (part ? atgt : asrc)[h*128 + tid] = s;
            }
        }
    } else {
        __syncthreads();
        float local = 0.f;
        const int base = z*4096;
        for (int idx = base + tid; idx < base + 4096; idx += 256) {
            const int i = idx>>7, k = idx&127;
            float s = 0.f;
            for (int q = 0; q < 32; ++q) {
                const float4 pi = *(const float4*)&projS[i*132 + q*4];
                const float4 pk = *(const float4*)&projS[k*132 + q*4];
                s += pi.x*pk.x + pi.y*pk.y + pi.z*pk.z + pi.w*pk.w;
            }
            if (i == k) s -= 1.f;
            local += s*s;
        }
        red[tid] = local;
        __syncthreads();
        for (int st = 128; st > 0; st >>= 1) {
            if (tid < st) red[tid] += red[tid+st];
            __syncthreads();
        }
        if (tid == 0) atomicAdd(&orth_part[h], red[0]);
        if (z == 0) {
            if (tid < 64) {
                float s = 0.f;
                for (int o = 0; o < 128; ++o) s += aH[o]*WH[o*320 + 256 + tid];
                arel[h*64 + tid] = s;
            }
            for (int idx = tid; idx < 8192; idx += 256) {
                const int r = idx & 63, o = idx >> 6;
                WcatT_bf[(size_t)o*256 + h*64 + r] = f2bf(WH[o*320 + 256 + r]);
            }
            if (h == 0 && tid == 0) {
                const float m = fmaxf(fmaxf(hw[0],hw[1]), fmaxf(hw[2],hw[3]));
                const float e0=expf(hw[0]-m), e1=expf(hw[1]-m), e2=expf(hw[2]-m), e3=expf(hw[3]-m);
                const float s = e0+e1+e2+e3;
                wsoft[0]=e0/s; wsoft[1]=e1/s; wsoft[2]=e2/s; wsoft[3]=e3/s;
            }
        }
    }
}

// LDS-tiled MFMA GEMM: block = 256 nodes x 128 cols (mat = blockIdx.y),
// M[mat] staged in LDS (XOR-swizzled), A-fragments in regs, 128 MFMA/wave.
// Output: tbl[n][1024], col = mat*128 + o.
__global__ __launch_bounds__(256) void k2_mfma(
    const u16* __restrict__ in_bf, const u16* __restrict__ M_bf,
    u16* __restrict__ tbl, int N)
{
    __shared__ u16 MS[16384];     // 32KB, rows XOR-swizzled in 16B units
    __shared__ u16 DS[128*136];   // 34.8KB D-repack buffer
    const int tid = threadIdx.x;
    const int w = tid >> 6, lane = tid & 63;
    const int mat = blockIdx.y;
    const int n0 = blockIdx.x*256;
    const int m = lane & 15, kg = lane >> 4;

    {   // stage M[mat] -> LDS, swizzled: byte = row*256 + ((c16*16) ^ ((row&7)<<4))
        const u16* Mp = M_bf + (size_t)mat*16384;
        for (int c = tid; c < 2048; c += 256) {
            const int row = c >> 4, c16 = c & 15;
            const u16x8 v = *(const u16x8*)(Mp + row*128 + c16*8);
            *(u16x8*)((char*)MS + row*256 + ((c16*16) ^ ((row&7)<<4))) = v;
        }
    }
    // A fragments: 4 row-tiles x 4 k-steps, direct from global (coalesced 16B)
    bf16x8 fa[4][4];
    #pragma unroll
    for (int rt = 0; rt < 4; ++rt) {
        int row = n0 + w*64 + rt*16 + m; if (row >= N) row = N-1;
        const u16* ap = in_bf + (size_t)row*128 + kg*8;
        #pragma unroll
        for (int ks = 0; ks < 4; ++ks) fa[rt][ks] = *(const bf16x8*)(ap + ks*32);
    }
    __syncthreads();

    f32x4 acc[4][8];
    #pragma unroll
    for (int rt = 0; rt < 4; ++rt)
        #pragma unroll
        for (int nt = 0; nt < 8; ++nt) { acc[rt][nt][0]=0.f; acc[rt][nt][1]=0.f; acc[rt][nt][2]=0.f; acc[rt][nt][3]=0.f; }

    #pragma unroll
    for (int nt = 0; nt < 8; ++nt) {
        const int o = nt*16 + m;
        bf16x8 fb[4];
        #pragma unroll
        for (int ks = 0; ks < 4; ++ks) {
            const int c16 = kg + 4*ks;
            fb[ks] = *(const bf16x8*)((const char*)MS + o*256 + ((c16*16) ^ ((o&7)<<4)));
        }
        #pragma unroll
        for (int rt = 0; rt < 4; ++rt)
            #pragma unroll
            for (int ks = 0; ks < 4; ++ks)
                acc[rt][nt] = __builtin_amdgcn_mfma_f32_16x16x32_bf16(fa[rt][ks], fb[ks], acc[rt][nt], 0, 0, 0);
    }

    // D repack + store, 2 phases of 128 rows (waves 0,1 then 2,3)
    for (int p = 0; p < 2; ++p) {
        __syncthreads();
        if ((w >> 1) == p) {
            #pragma unroll
            for (int rt = 0; rt < 4; ++rt) {
                const int r0 = (w&1)*64 + rt*16 + kg*4;
                #pragma unroll
                for (int nt = 0; nt < 8; ++nt) {
                    const int o = nt*16 + m;
                    #pragma unroll
                    for (int r = 0; r < 4; ++r)
                        DS[(r0+r)*136 + o] = f2bf(acc[rt][nt][r]);
                }
            }
        }
        __syncthreads();
        for (int idx = tid; idx < 2048; idx += 256) {
            const int row = idx >> 4, seg = idx & 15;
            const int n = n0 + p*128 + row;
            if (n < N) {
                const bf16x8 v = *(const bf16x8*)&DS[row*136 + seg*8];
                *(bf16x8*)(tbl + (size_t)n*1024 + mat*128 + seg*8) = v;
            }
        }
    }
}

__global__ __launch_bounds__(256) void k2b_scores(
    const float* __restrict__ input, const float* __restrict__ asrc, const float* __restrict__ atgt,
    float* __restrict__ s_src, float* __restrict__ s_tgt, int N)
{
    __shared__ float aS[512], tS[512];
    const int tid = threadIdx.x;
    for (int idx = tid; idx < 512; idx += 256) { aS[idx] = asrc[idx]; tS[idx] = atgt[idx]; }
    __syncthreads();
    const int n = blockIdx.x*256 + tid;
    if (n >= N) return;
    const float4* inr = (const float4*)(input + (size_t)n*128);
    float ss[4] = {0.f,0.f,0.f,0.f}, st[4] = {0.f,0.f,0.f,0.f};
    for (int q = 0; q < 32; ++q) {
        const float4 v = inr[q];
        #pragma unroll
        for (int hh = 0; hh < 4; ++hh) {
            const float4 av = *(const float4*)&aS[hh*128 + q*4];
            const float4 tv = *(const float4*)&tS[hh*128 + q*4];
            ss[hh] += v.x*av.x + v.y*av.y + v.z*av.z + v.w*av.w;
            st[hh] += v.x*tv.x + v.y*tv.y + v.z*tv.z + v.w*tv.w;
        }
    }
    float4 o1; o1.x=ss[0]; o1.y=ss[1]; o1.z=ss[2]; o1.w=ss[3];
    float4 o2; o2.x=st[0]; o2.y=st[1]; o2.z=st[2]; o2.w=st[3];
    *(float4*)(s_src + (size_t)n*4) = o1;
    *(float4*)(s_tgt + (size_t)n*4) = o2;
}

__global__ __launch_bounds__(256) void k3_edges(
    const int* __restrict__ edge, const int* __restrict__ nhop,
    const float* __restrict__ emb1, const float* __restrict__ emb2,
    const float* __restrict__ s_src, const float* __restrict__ s_tgt,
    const float* __restrict__ arel,
    float* __restrict__ edge_e, float* __restrict__ rowsum, int* __restrict__ deg,
    u16* __restrict__ emb_bf,
    int E1, int E2)
{
    __shared__ float arelS[256];
    const int tid = threadIdx.x;
    arelS[tid] = arel[tid];
    __syncthreads();
    const int E = E1 + E2;
    const int e = blockIdx.x*256 + tid;
    if (e >= E) return;
    int src, tgt; const float* er;
    if (e < E1) { src = edge[e]; tgt = edge[E1+e]; er = emb1 + (size_t)e*64; }
    else { const int e2 = e-E1; src = nhop[e2]; tgt = nhop[E2+e2]; er = emb2 + (size_t)e2*64; }
    float sr[4] = {0.f,0.f,0.f,0.f};
    const float4* er4 = (const float4*)er;
    u16* eb = emb_bf + (size_t)e*64;
    for (int q = 0; q < 16; ++q) {
        const float4 v = er4[q];
        u16x4 pk; pk.x=f2bf(v.x); pk.y=f2bf(v.y); pk.z=f2bf(v.z); pk.w=f2bf(v.w);
        *(u16x4*)(eb + q*4) = pk;
        #pragma unroll
        for (int hh = 0; hh < 4; ++hh) {
            const float4 av = *(const float4*)&arelS[hh*64 + q*4];
            sr[hh] += v.x*av.x + v.y*av.y + v.z*av.z + v.w*av.w;
        }
    }
    const float4 s4 = *(const float4*)(s_src + (size_t)src*4);
    const float4 t4 = *(const float4*)(s_tgt + (size_t)tgt*4);
    const float sv[4] = {s4.x,s4.y,s4.z,s4.w};
    const float tv[4] = {t4.x,t4.y,t4.z,t4.w};
    float ee[4];
    #pragma unroll
    for (int hh = 0; hh < 4; ++hh) {
        const float sc = sv[hh] + tv[hh] + sr[hh];
        const float p = (sc > 0.f) ? -sc : (-0.2f*sc);
        ee[hh] = expf(p);
        atomicAdd(&rowsum[(size_t)src*4 + hh], ee[hh]);
    }
    float4 eo; eo.x=ee[0]; eo.y=ee[1]; eo.z=ee[2]; eo.w=ee[3];
    *(float4*)(edge_e + (size_t)e*4) = eo;
    atomicAdd(&deg[src], 1);
}

__global__ __launch_bounds__(1024) void k_scanA(const int* __restrict__ deg, int* __restrict__ offsets,
                                                int* __restrict__ bsum, int N)
{
    __shared__ int wsumS[16];
    const int tid = threadIdx.x;
    const int lane = tid & 63, wid = tid >> 6;
    const int i0 = blockIdx.x*4096 + tid*4;
    int a0=0,a1=0,a2=0,a3=0;
    if (i0 + 3 < N) { const int4 t = *(const int4*)(deg + i0); a0=t.x; a1=t.y; a2=t.z; a3=t.w; }
    else { if (i0 < N) a0=deg[i0]; if (i0+1 < N) a1=deg[i0+1]; if (i0+2 < N) a2=deg[i0+2]; }
    const int s1=a0+a1, s2=s1+a2, s3=s2+a3;
    int s = s3;
    #pragma unroll
    for (int d = 1; d < 64; d <<= 1) { const int t = __shfl_up(s, d); if (lane >= d) s += t; }
    if (lane == 63) wsumS[wid] = s;
    __syncthreads();
    if (tid < 16) {
        int t = wsumS[tid];
        #pragma unroll
        for (int d = 1; d < 16; d <<= 1) { const int u = __shfl_up(t, d); if (tid >= d) t += u; }
        wsumS[tid] = t;
    }
    __syncthreads();
    const int ex = (wid ? wsumS[wid-1] : 0) + s - s3;
    if (i0 < N)     offsets[i0]   = ex;
    if (i0+1 < N)   offsets[i0+1] = ex + a0;
    if (i0+2 < N)   offsets[i0+2] = ex + s1;
    if (i0+3 < N)   offsets[i0+3] = ex + s2;
    if (tid == 0) bsum[blockIdx.x] = wsumS[15];
}

__global__ __launch_bounds__(64) void k_scanB(const int* __restrict__ bsum, int* __restrict__ boff,
                                              int* __restrict__ offsets, int nb, int N)
{
    const int tid = threadIdx.x;
    const int v = (tid < nb) ? bsum[tid] : 0;
    int s = v;
    #pragma unroll
    for (int d = 1; d < 64; d <<= 1) { const int t = __shfl_up(s, d); if (tid >= d) s += t; }
    if (tid < nb) boff[tid] = s - v;
    if (tid == 63) offsets[N] = s;
}

__global__ __launch_bounds__(256) void k_scanC(int* __restrict__ offsets, const int* __restrict__ boff, int N)
{
    const int i = blockIdx.x*256 + threadIdx.x;
    if (i < N) offsets[i] += boff[i >> 12];
}

__global__ __launch_bounds__(256) void k_fill(
    const int* __restrict__ edge, const int* __restrict__ nhop,
    const float* __restrict__ edge_e,
    const int* __restrict__ offsets, int* __restrict__ cursor,
    int* __restrict__ csr_e, int* __restrict__ csr_tgt, float* __restrict__ ee_perm,
    int E1, int E2)
{
    const int E = E1+E2;
    const int e = blockIdx.x*256 + threadIdx.x;
    if (e >= E) return;
    int src, tgt;
    if (e < E1) { src = edge[e]; tgt = edge[E1+e]; }
    else { const int e2 = e-E1; src = nhop[e2]; tgt = nhop[E2+e2]; }
    const int pos = atomicAdd(&cursor[src], 1);
    const int p = offsets[src] + pos;
    csr_e[p] = e;
    csr_tgt[p] = tgt;
    *(float4*)(ee_perm + (size_t)p*4) = *(const float4*)(edge_e + (size_t)e*4);
}

// per-node wave gather over merged tbl. lane l: head hl=l>>4, dims (l&15)*8..+7.
__global__ __launch_bounds__(256) void k4_gather(
    const float* __restrict__ ee_perm, const int* __restrict__ offsets,
    const int* __restrict__ csr_e, const int* __restrict__ csr_tgt,
    const u16* __restrict__ emb_bf,
    const u16* __restrict__ tbl,
    const float* __restrict__ rowsum, const float* __restrict__ wsoft,
    float* __restrict__ pout, u16* __restrict__ semb_bf,
    int N)
{
    const int lane = threadIdx.x & 63;
    const int n = blockIdx.x*4 + (threadIdx.x >> 6);
    if (n >= N) return;
    const int hl = lane >> 4;
    const int hoff = hl*128 + (lane & 15)*8;

    union HT { u16x8 v; unsigned u[4]; };

    const float4 rs4 = *(const float4*)(rowsum + (size_t)n*4);
    const float rsh = (hl==0)?rs4.x:(hl==1)?rs4.y:(hl==2)?rs4.z:rs4.w;
    float acc[8];
    {
        HT hs; hs.v = *(const u16x8*)(tbl + (size_t)n*1024 + hoff);
        #pragma unroll
        for (int p = 0; p < 4; ++p) {
            union{unsigned u; float f;} lo, hi;
            lo.u = hs.u[p] << 16; hi.u = hs.u[p] & 0xffff0000u;
            acc[2*p]   = rsh*lo.f;
            acc[2*p+1] = rsh*hi.f;
        }
    }
    float sm0=0.f, sm1=0.f, sm2=0.f, sm3=0.f;

    const int start = offsets[n], end = offsets[n+1];
    for (int cb = start; cb < end; cb += 64) {
        const int cnt = (end - cb < 64) ? (end - cb) : 64;
        int eL = 0, tgtL = 0;
        float4 eeL; eeL.x=0.f; eeL.y=0.f; eeL.z=0.f; eeL.w=0.f;
        if (cb + lane < end) {
            eL   = csr_e[cb + lane];
            tgtL = csr_tgt[cb + lane];
            eeL  = *(const float4*)(ee_perm + (size_t)(cb + lane)*4);
        }
        int tgt_c = __shfl(tgtL, 0), e_c = __shfl(eL, 0);
        HT ht; ht.v = *(const u16x8*)(tbl + (size_t)tgt_c*1024 + 512 + hoff);
        u16 em = emb_bf[(size_t)e_c*64 + lane];
        for (int i = 0; i < cnt; ++i) {
            const float e0 = __shfl(eeL.x, i);
            const float e1 = __shfl(eeL.y, i);
            const float e2 = __shfl(eeL.z, i);
            const float e3 = __shfl(eeL.w, i);
            const int ip = (i+1 < cnt) ? (i+1) : i;
            const int tgt_n = __shfl(tgtL, ip);
            const int e_n   = __shfl(eL, ip);
            HT htn; htn.v = *(const u16x8*)(tbl + (size_t)tgt_n*1024 + 512 + hoff);
            const u16 emn = emb_bf[(size_t)e_n*64 + lane];
            const float eh = (hl==0)?e0:(hl==1)?e1:(hl==2)?e2:e3;
            #pragma unroll
            for (int p = 0; p < 4; ++p) {
                union{unsigned u; float f;} lo, hi;
                lo.u = ht.u[p] << 16; hi.u = ht.u[p] & 0xffff0000u;
                acc[2*p]   += eh*lo.f;
                acc[2*p+1] += eh*hi.f;
            }
            const float ev = bf2f(em);
            sm0 += e0*ev; sm1 += e1*ev; sm2 += e2*ev; sm3 += e3*ev;
            ht = htn; em = emn;
        }
    }
    const float4 ws4 = *(const float4*)wsoft;
    const float wh = (hl==0)?ws4.x:(hl==1)?ws4.y:(hl==2)?ws4.z:ws4.w;
    float p[8];
    #pragma unroll
    for (int j = 0; j < 8; ++j) {
        float pv = wh*acc[j];
        pv += __shfl_xor(pv, 16);
        pv += __shfl_xor(pv, 32);
        p[j] = pv;
    }
    if (hl == 0) {
        float* op = pout + (size_t)n*128 + (lane & 15)*8;
        float4 A; A.x=p[0]; A.y=p[1]; A.z=p[2]; A.w=p[3];
        float4 B; B.x=p[4]; B.y=p[5]; B.z=p[6]; B.w=p[7];
        *(float4*)op = A;
        *(float4*)(op+4) = B;
    }
    u16* so = semb_bf + (size_t)n*256;
    so[lane]       = f2bf(ws4.x*sm0);
    so[64 + lane]  = f2bf(ws4.y*sm1);
    so[128 + lane] = f2bf(ws4.z*sm2);
    so[192 + lane] = f2bf(ws4.w*sm3);
}

// MFMA GEMM: out_add = semb_bf (N x 256) @ WcatT^T (256 x 128); fused epilogue.
__global__ __launch_bounds__(256) void k5_gemm(
    const u16* __restrict__ semb_bf, const u16* __restrict__ wcatT_bf,
    const float* __restrict__ rowsum, const float* __restrict__ orth_part,
    float* __restrict__ out, int N)
{
    __shared__ float DS[64*132];
    const int tid = threadIdx.x;
    if (blockIdx.x == 0 && tid == 0)
        out[(size_t)N*128] = 0.01f*(sqrtf(orth_part[0])+sqrtf(orth_part[1])+sqrtf(orth_part[2])+sqrtf(orth_part[3]));
    const int w = tid >> 6, lane = tid & 63;
    const int m = lane & 15, kg = lane >> 4;
    const int n0 = blockIdx.x*64;

    bf16x8 fa[8];
    {
        int row = n0 + w*16 + m; if (row >= N) row = N-1;
        const u16* ap = semb_bf + (size_t)row*256 + kg*8;
        #pragma unroll
        for (int ks = 0; ks < 8; ++ks) fa[ks] = *(const bf16x8*)(ap + ks*32);
    }
    f32x4 acc[8];
    #pragma unroll
    for (int nt = 0; nt < 8; ++nt) { acc[nt][0]=0.f; acc[nt][1]=0.f; acc[nt][2]=0.f; acc[nt][3]=0.f; }
    #pragma unroll
    for (int nt = 0; nt < 8; ++nt) {
        const u16* bp = wcatT_bf + (size_t)(nt*16 + m)*256 + kg*8;
        #pragma unroll
        for (int ks = 0; ks < 8; ++ks) {
            const bf16x8 fb = *(const bf16x8*)(bp + ks*32);
            acc[nt] = __builtin_amdgcn_mfma_f32_16x16x32_bf16(fa[ks], fb, acc[nt], 0, 0, 0);
        }
    }
    #pragma unroll
    for (int nt = 0; nt < 8; ++nt) {
        const int o = nt*16 + m;
        const int r0 = w*16 + kg*4;
        #pragma unroll
        for (int r = 0; r < 4; ++r)
            DS[(r0+r)*132 + o] = acc[nt][r];
    }
    __syncthreads();
    for (int idx = tid; idx < 2048; idx += 256) {
        const int row = idx >> 5, q = idx & 31;
        const int n = n0 + row;
        if (n < N) {
            const float4 d = *(const float4*)&DS[row*132 + q*4];
            float* op = out + (size_t)n*128 + q*4;
            const float4 pv = *(const float4*)op;
            const float rinv = 1.0f / fmaxf(rowsum[(size_t)n*4 + 3], 1e-12f);
            float v0 = (pv.x + d.x)*rinv;
            float v1 = (pv.y + d.y)*rinv;
            float v2 = (pv.z + d.z)*rinv;
            float v3 = (pv.w + d.w)*rinv;
            v0 = (v0 > 0.f) ? v0 : expm1f(v0);
            v1 = (v1 > 0.f) ? v1 : expm1f(v1);
            v2 = (v2 > 0.f) ? v2 : expm1f(v2);
            v3 = (v3 > 0.f) ? v3 : expm1f(v3);
            float4 r4; r4.x=v0; r4.y=v1; r4.z=v2; r4.w=v3;
            *(float4*)op = r4;
        }
    }
}

extern "C" void kernel_launch(void* const* d_in, const int* in_sizes, int n_in,
                              void* d_out, int out_size, void* d_ws, size_t ws_size,
                              hipStream_t stream)
{
    const float* input = (const float*)d_in[0];
    const int*   edge  = (const int*)d_in[1];
    const float* emb1  = (const float*)d_in[2];
    const int*   nhop  = (const int*)d_in[3];
    const float* emb2  = (const float*)d_in[4];
    const float* proj  = (const float*)d_in[5];
    const float* W     = (const float*)d_in[6];
    const float* a     = (const float*)d_in[7];
    const float* hw    = (const float*)d_in[8];
    float* out = (float*)d_out;

    const int N  = in_sizes[0] / 128;
    const int E1 = in_sizes[1] / 2;
    const int E2 = in_sizes[3] / 2;
    const int E  = E1 + E2;
    (void)n_in; (void)out_size; (void)ws_size;

    char* wsb = (char*)d_ws;
    size_t off = 0;
    auto alloc = [&](size_t bytes) -> char* {
        char* p = wsb + off;
        off += (bytes + 255) & ~(size_t)255;
        return p;
    };
    u16*   in_bf    = (u16*)alloc((size_t)N*128*2);
    u16*   tbl      = (u16*)alloc((size_t)N*1024*2);
    u16*   semb_bf  = (u16*)alloc((size_t)N*256*2);
    u16*   emb_bf   = (u16*)alloc((size_t)E*64*2);
    float* edge_e   = (float*)alloc((size_t)E*4*4);
    float* ee_perm  = (float*)alloc((size_t)E*4*4);
    int*   csr_e    = (int*)alloc((size_t)E*4);
    int*   csr_tgt  = (int*)alloc((size_t)E*4);
    u16*   M_bf     = (u16*)alloc((size_t)8*16384*2);
    u16*   WcatT_bf = (u16*)alloc((size_t)128*256*2);
    float* asrc     = (float*)alloc(512*4);
    float* atgt     = (float*)alloc(512*4);
    float* arel     = (float*)alloc(256*4);
    float* s_src    = (float*)alloc((size_t)N*4*4);
    float* s_tgt    = (float*)alloc((size_t)N*4*4);
    float* wsoft    = (float*)alloc(4*4);
    int*   offsets  = (int*)alloc((size_t)(N+1)*4);
    int*   bsum     = (int*)alloc(64*4);
    int*   boff     = (int*)alloc(64*4);
    const size_t zoff0 = off;
    float* rowsum   = (float*)alloc((size_t)N*4*4);
    float* orth_part= (float*)alloc(4*4);
    int*   deg      = (int*)alloc((size_t)N*4);
    int*   cursor   = (int*)alloc((size_t)N*4);
    const size_t zoff1 = off;

    hipMemsetAsync(wsb + zoff0, 0, zoff1 - zoff0, stream);

    const int nbScan = (N + 4095) / 4096;

    kc_bf16<<<dim3((N*128/8 + 255)/256), dim3(256), 0, stream>>>(input, in_bf, N*128/8);
    k1_prep<<<dim3(NHEAD,3,4), dim3(256), 0, stream>>>(proj, W, a, hw, M_bf,
                                                       asrc, atgt, arel, WcatT_bf, wsoft, orth_part);
    k2_mfma<<<dim3((N+255)/256, 8), dim3(256), 0, stream>>>(in_bf, M_bf, tbl, N);
    k2b_scores<<<dim3((N+255)/256), dim3(256), 0, stream>>>(input, asrc, atgt, s_src, s_tgt, N);
    k3_edges<<<dim3((E+255)/256), dim3(256), 0, stream>>>(edge, nhop, emb1, emb2, s_src, s_tgt,
                                                          arel, edge_e, rowsum, deg, emb_bf, E1, E2);
    k_scanA<<<dim3(nbScan), dim3(1024), 0, stream>>>(deg, offsets, bsum, N);
    k_scanB<<<dim3(1), dim3(64), 0, stream>>>(bsum, boff, offsets, nbScan, N);
    k_scanC<<<dim3((N+255)/256), dim3(256), 0, stream>>>(offsets, boff, N);
    k_fill<<<dim3((E+255)/256), dim3(256), 0, stream>>>(edge, nhop, edge_e, offsets, cursor,
                                                        csr_e, csr_tgt, ee_perm, E1, E2);
    k4_gather<<<dim3((N+3)/4), dim3(256), 0, stream>>>(ee_perm, offsets, csr_e, csr_tgt, emb_bf,
                                                       tbl, rowsum, wsoft,
                                                       out, semb_bf, N);
    k5_gemm<<<dim3((N+63)/64), dim3(256), 0, stream>>>(semb_bf, WcatT_bf, rowsum, orth_part,
                                                       out, N);
}

// Round 5
// 275.747 us; speedup vs baseline: 3.7213x; 1.1678x over previous
//
#include <hip/hip_runtime.h>
#include <math.h>

// SpGraphAttentionLayer on MI355X — round 5.
// k3: cooperative 16-lane-per-edge (coalesced 1KB/wave emb reads), no rowsum atomics.
// k4: depth-4 software-pipelined gather; computes rowsum internally (lane partials +
//     butterfly reduce), writes rowsum3[n] for k5. kc_bf16 fused into k0_nodes.

#define NHEAD 4

typedef unsigned short u16;
typedef __attribute__((ext_vector_type(4))) unsigned short u16x4;
typedef __attribute__((ext_vector_type(8))) unsigned short u16x8;
typedef __attribute__((ext_vector_type(8))) short bf16x8;
typedef __attribute__((ext_vector_type(4))) float f32x4;

__device__ __forceinline__ float bf2f(u16 v) {
    union { unsigned u; float f; } x; x.u = ((unsigned)v) << 16; return x.f;
}
__device__ __forceinline__ u16 f2bf(float f) {
    union { float f; unsigned u; } x; x.f = f;
    const unsigned r = x.u + 0x7FFFu + ((x.u >> 16) & 1u);
    return (u16)(r >> 16);
}

__global__ __launch_bounds__(256) void k1_prep(
    const float* __restrict__ proj, const float* __restrict__ W,
    const float* __restrict__ a, const float* __restrict__ hw,
    u16* __restrict__ M_bf,
    float* __restrict__ asrc, float* __restrict__ atgt, float* __restrict__ arel,
    u16* __restrict__ WcatT_bf, float* __restrict__ wsoft,
    float* __restrict__ orth_part)
{
    __shared__ float projS[128*132];
    __shared__ float WS[32*132];
    __shared__ float tS[128];
    __shared__ float red[256];
    const int h = blockIdx.x;
    const int part = blockIdx.y;
    const int z = blockIdx.z;
    const int tid = threadIdx.x;
    const float* projH = proj + h*(128*128);
    const float* WH = W + h*(128*320);
    const float* aH = a + h*128;

    {
        const float4* p4 = (const float4*)projH;
        for (int idx = tid; idx < 4096; idx += 256)
            *(float4*)&projS[(idx>>5)*132 + (idx&31)*4] = p4[idx];
    }

    if (part < 2) {
        const int koff = part ? 128 : 0;
        for (int idx = tid; idx < 1024; idx += 256) {
            const int ol = idx>>5, jq = idx&31;
            *(float4*)&WS[ol*132 + jq*4] = *(const float4*)&WH[(z*32+ol)*320 + koff + jq*4];
        }
        __syncthreads();
        u16* Mout = M_bf + ((size_t)(part*4 + h))*16384;
        for (int idx = tid; idx < 1024; idx += 256) {
            const int ol = idx>>5, jq = idx&31;
            float4 acc; acc.x=0.f; acc.y=0.f; acc.z=0.f; acc.w=0.f;
            for (int i = 0; i < 128; ++i) {
                const float wv = WS[ol*132 + i];
                const float4 pv = *(const float4*)&projS[i*132 + jq*4];
                acc.x += wv*pv.x; acc.y += wv*pv.y; acc.z += wv*pv.z; acc.w += wv*pv.w;
            }
            u16x4 pk; pk.x=f2bf(acc.x); pk.y=f2bf(acc.y); pk.z=f2bf(acc.z); pk.w=f2bf(acc.w);
            *(u16x4*)&Mout[(z*32+ol)*128 + jq*4] = pk;
        }
        if (z == 0) {
            if (tid < 128) {
                float s = 0.f;
                for (int o = 0; o < 128; ++o) s += aH[o]*WH[o*320 + koff + tid];
                tS[tid] = s;
            }
            __syncthreads();
            if (tid < 128) {
                float s = 0.f;
                for (int i = 0; i < 128; ++i) s += tS[i]*projS[i*132 + tid];
                (part ? atgt : asrc)[h*128 + tid] = s;
            }
        }
    } else {
        __syncthreads();
        float local = 0.f;
        const int base = z*4096;
        for (int idx = base + tid; idx < base + 4096; idx += 256) {
            const int i = idx>>7, k = idx&127;
            float s = 0.f;
            for (int q = 0; q < 32; ++q) {
                const float4 pi = *(const float4*)&projS[i*132 + q*4];
                const float4 pk = *(const float4*)&projS[k*132 + q*4];
                s += pi.x*pk.x + pi.y*pk.y + pi.z*pk.z + pi.w*pk.w;
            }
            if (i == k) s -= 1.f;
            local += s*s;
        }
        red[tid] = local;
        __syncthreads();
        for (int st = 128; st > 0; st >>= 1) {
            if (tid < st) red[tid] += red[tid+st];
            __syncthreads();
        }
        if (tid == 0) atomicAdd(&orth_part[h], red[0]);
        if (z == 0) {
            if (tid < 64) {
                float s = 0.f;
                for (int o = 0; o < 128; ++o) s += aH[o]*WH[o*320 + 256 + tid];
                arel[h*64 + tid] = s;
            }
            for (int idx = tid; idx < 8192; idx += 256) {
                const int r = idx & 63, o = idx >> 6;
                WcatT_bf[(size_t)o*256 + h*64 + r] = f2bf(WH[o*320 + 256 + r]);
            }
            if (h == 0 && tid == 0) {
                const float m = fmaxf(fmaxf(hw[0],hw[1]), fmaxf(hw[2],hw[3]));
                const float e0=expf(hw[0]-m), e1=expf(hw[1]-m), e2=expf(hw[2]-m), e3=expf(hw[3]-m);
                const float s = e0+e1+e2+e3;
                wsoft[0]=e0/s; wsoft[1]=e1/s; wsoft[2]=e2/s; wsoft[3]=e3/s;
            }
        }
    }
}

// fused: input -> bf16 + per-node score partials (one read of input)
__global__ __launch_bounds__(256) void k0_nodes(
    const float* __restrict__ input, const float* __restrict__ asrc, const float* __restrict__ atgt,
    u16* __restrict__ in_bf, float* __restrict__ s_src, float* __restrict__ s_tgt, int N)
{
    __shared__ float aS[512], tS[512];
    const int tid = threadIdx.x;
    for (int idx = tid; idx < 512; idx += 256) { aS[idx] = asrc[idx]; tS[idx] = atgt[idx]; }
    __syncthreads();
    const int n = blockIdx.x*256 + tid;
    if (n >= N) return;
    const float4* inr = (const float4*)(input + (size_t)n*128);
    u16* ob = in_bf + (size_t)n*128;
    float ss[4] = {0.f,0.f,0.f,0.f}, st[4] = {0.f,0.f,0.f,0.f};
    for (int q = 0; q < 32; ++q) {
        const float4 v = inr[q];
        u16x4 pk; pk.x=f2bf(v.x); pk.y=f2bf(v.y); pk.z=f2bf(v.z); pk.w=f2bf(v.w);
        *(u16x4*)(ob + q*4) = pk;
        #pragma unroll
        for (int hh = 0; hh < 4; ++hh) {
            const float4 av = *(const float4*)&aS[hh*128 + q*4];
            const float4 tv = *(const float4*)&tS[hh*128 + q*4];
            ss[hh] += v.x*av.x + v.y*av.y + v.z*av.z + v.w*av.w;
            st[hh] += v.x*tv.x + v.y*tv.y + v.z*tv.z + v.w*tv.w;
        }
    }
    float4 o1; o1.x=ss[0]; o1.y=ss[1]; o1.z=ss[2]; o1.w=ss[3];
    float4 o2; o2.x=st[0]; o2.y=st[1]; o2.z=st[2]; o2.w=st[3];
    *(float4*)(s_src + (size_t)n*4) = o1;
    *(float4*)(s_tgt + (size_t)n*4) = o2;
}

// LDS-tiled MFMA GEMM (unchanged from round 4)
__global__ __launch_bounds__(256) void k2_mfma(
    const u16* __restrict__ in_bf, const u16* __restrict__ M_bf,
    u16* __restrict__ tbl, int N)
{
    __shared__ u16 MS[16384];
    __shared__ u16 DS[128*136];
    const int tid = threadIdx.x;
    const int w = tid >> 6, lane = tid & 63;
    const int mat = blockIdx.y;
    const int n0 = blockIdx.x*256;
    const int m = lane & 15, kg = lane >> 4;

    {
        const u16* Mp = M_bf + (size_t)mat*16384;
        for (int c = tid; c < 2048; c += 256) {
            const int row = c >> 4, c16 = c & 15;
            const u16x8 v = *(const u16x8*)(Mp + row*128 + c16*8);
            *(u16x8*)((char*)MS + row*256 + ((c16*16) ^ ((row&7)<<4))) = v;
        }
    }
    bf16x8 fa[4][4];
    #pragma unroll
    for (int rt = 0; rt < 4; ++rt) {
        int row = n0 + w*64 + rt*16 + m; if (row >= N) row = N-1;
        const u16* ap = in_bf + (size_t)row*128 + kg*8;
        #pragma unroll
        for (int ks = 0; ks < 4; ++ks) fa[rt][ks] = *(const bf16x8*)(ap + ks*32);
    }
    __syncthreads();

    f32x4 acc[4][8];
    #pragma unroll
    for (int rt = 0; rt < 4; ++rt)
        #pragma unroll
        for (int nt = 0; nt < 8; ++nt) { acc[rt][nt][0]=0.f; acc[rt][nt][1]=0.f; acc[rt][nt][2]=0.f; acc[rt][nt][3]=0.f; }

    #pragma unroll
    for (int nt = 0; nt < 8; ++nt) {
        const int o = nt*16 + m;
        bf16x8 fb[4];
        #pragma unroll
        for (int ks = 0; ks < 4; ++ks) {
            const int c16 = kg + 4*ks;
            fb[ks] = *(const bf16x8*)((const char*)MS + o*256 + ((c16*16) ^ ((o&7)<<4)));
        }
        #pragma unroll
        for (int rt = 0; rt < 4; ++rt)
            #pragma unroll
            for (int ks = 0; ks < 4; ++ks)
                acc[rt][nt] = __builtin_amdgcn_mfma_f32_16x16x32_bf16(fa[rt][ks], fb[ks], acc[rt][nt], 0, 0, 0);
    }

    for (int p = 0; p < 2; ++p) {
        __syncthreads();
        if ((w >> 1) == p) {
            #pragma unroll
            for (int rt = 0; rt < 4; ++rt) {
                const int r0 = (w&1)*64 + rt*16 + kg*4;
                #pragma unroll
                for (int nt = 0; nt < 8; ++nt) {
                    const int o = nt*16 + m;
                    #pragma unroll
                    for (int r = 0; r < 4; ++r)
                        DS[(r0+r)*136 + o] = f2bf(acc[rt][nt][r]);
                }
            }
        }
        __syncthreads();
        for (int idx = tid; idx < 2048; idx += 256) {
            const int row = idx >> 4, seg = idx & 15;
            const int n = n0 + p*128 + row;
            if (n < N) {
                const bf16x8 v = *(const bf16x8*)&DS[row*136 + seg*8];
                *(bf16x8*)(tbl + (size_t)n*1024 + mat*128 + seg*8) = v;
            }
        }
    }
}

// cooperative per-edge: 16 lanes per edge; wave reads 4 consecutive 256B emb rows (1KB coalesced).
// group leader gathers scores, computes edge_e, bumps deg. No rowsum atomics.
__global__ __launch_bounds__(256) void k3_edges(
    const int* __restrict__ edge, const int* __restrict__ nhop,
    const float* __restrict__ emb1, const float* __restrict__ emb2,
    const float* __restrict__ s_src, const float* __restrict__ s_tgt,
    const float* __restrict__ arel,
    float* __restrict__ edge_e, int* __restrict__ deg,
    u16* __restrict__ emb_bf, int E1, int E2)
{
    const int tid = threadIdx.x;
    const int g = tid >> 4, l = tid & 15;
    const int E = E1 + E2;
    const float4 ar0 = *(const float4*)(arel + 0*64 + l*4);
    const float4 ar1 = *(const float4*)(arel + 1*64 + l*4);
    const float4 ar2 = *(const float4*)(arel + 2*64 + l*4);
    const float4 ar3 = *(const float4*)(arel + 3*64 + l*4);
    const int ebase = blockIdx.x*256;
    #pragma unroll 4
    for (int it = 0; it < 16; ++it) {
        const int e = ebase + it*16 + g;
        if (e >= E) continue;               // group-uniform guard
        const float4 v = (e < E1) ? *(const float4*)(emb1 + (size_t)e*64 + l*4)
                                  : *(const float4*)(emb2 + (size_t)(e-E1)*64 + l*4);
        u16x4 pk; pk.x=f2bf(v.x); pk.y=f2bf(v.y); pk.z=f2bf(v.z); pk.w=f2bf(v.w);
        *(u16x4*)(emb_bf + (size_t)e*64 + l*4) = pk;
        float p0 = v.x*ar0.x + v.y*ar0.y + v.z*ar0.z + v.w*ar0.w;
        float p1 = v.x*ar1.x + v.y*ar1.y + v.z*ar1.z + v.w*ar1.w;
        float p2 = v.x*ar2.x + v.y*ar2.y + v.z*ar2.z + v.w*ar2.w;
        float p3 = v.x*ar3.x + v.y*ar3.y + v.z*ar3.z + v.w*ar3.w;
        #pragma unroll
        for (int d = 1; d < 16; d <<= 1) {
            p0 += __shfl_xor(p0, d);
            p1 += __shfl_xor(p1, d);
            p2 += __shfl_xor(p2, d);
            p3 += __shfl_xor(p3, d);
        }
        if (l == 0) {
            int src, tgt;
            if (e < E1) { src = edge[e]; tgt = edge[E1+e]; }
            else { const int e2 = e-E1; src = nhop[e2]; tgt = nhop[E2+e2]; }
            const float4 s4 = *(const float4*)(s_src + (size_t)src*4);
            const float4 t4 = *(const float4*)(s_tgt + (size_t)tgt*4);
            float4 eo;
            { const float sc = s4.x+t4.x+p0; eo.x = expf(sc>0.f ? -sc : -0.2f*sc); }
            { const float sc = s4.y+t4.y+p1; eo.y = expf(sc>0.f ? -sc : -0.2f*sc); }
            { const float sc = s4.z+t4.z+p2; eo.z = expf(sc>0.f ? -sc : -0.2f*sc); }
            { const float sc = s4.w+t4.w+p3; eo.w = expf(sc>0.f ? -sc : -0.2f*sc); }
            *(float4*)(edge_e + (size_t)e*4) = eo;
            atomicAdd(&deg[src], 1);
        }
    }
}

__global__ __launch_bounds__(1024) void k_scanA(const int* __restrict__ deg, int* __restrict__ offsets,
                                                int* __restrict__ bsum, int N)
{
    __shared__ int wsumS[16];
    const int tid = threadIdx.x;
    const int lane = tid & 63, wid = tid >> 6;
    const int i0 = blockIdx.x*4096 + tid*4;
    int a0=0,a1=0,a2=0,a3=0;
    if (i0 + 3 < N) { const int4 t = *(const int4*)(deg + i0); a0=t.x; a1=t.y; a2=t.z; a3=t.w; }
    else { if (i0 < N) a0=deg[i0]; if (i0+1 < N) a1=deg[i0+1]; if (i0+2 < N) a2=deg[i0+2]; }
    const int s1=a0+a1, s2=s1+a2, s3=s2+a3;
    int s = s3;
    #pragma unroll
    for (int d = 1; d < 64; d <<= 1) { const int t = __shfl_up(s, d); if (lane >= d) s += t; }
    if (lane == 63) wsumS[wid] = s;
    __syncthreads();
    if (tid < 16) {
        int t = wsumS[tid];
        #pragma unroll
        for (int d = 1; d < 16; d <<= 1) { const int u = __shfl_up(t, d); if (tid >= d) t += u; }
        wsumS[tid] = t;
    }
    __syncthreads();
    const int ex = (wid ? wsumS[wid-1] : 0) + s - s3;
    if (i0 < N)     offsets[i0]   = ex;
    if (i0+1 < N)   offsets[i0+1] = ex + a0;
    if (i0+2 < N)   offsets[i0+2] = ex + s1;
    if (i0+3 < N)   offsets[i0+3] = ex + s2;
    if (tid == 0) bsum[blockIdx.x] = wsumS[15];
}

__global__ __launch_bounds__(64) void k_scanB(const int* __restrict__ bsum, int* __restrict__ boff,
                                              int* __restrict__ offsets, int nb, int N)
{
    const int tid = threadIdx.x;
    const int v = (tid < nb) ? bsum[tid] : 0;
    int s = v;
    #pragma unroll
    for (int d = 1; d < 64; d <<= 1) { const int t = __shfl_up(s, d); if (tid >= d) s += t; }
    if (tid < nb) boff[tid] = s - v;
    if (tid == 63) offsets[N] = s;
}

__global__ __launch_bounds__(256) void k_scanC(int* __restrict__ offsets, const int* __restrict__ boff, int N)
{
    const int i = blockIdx.x*256 + threadIdx.x;
    if (i < N) offsets[i] += boff[i >> 12];
}

__global__ __launch_bounds__(256) void k_fill(
    const int* __restrict__ edge, const int* __restrict__ nhop,
    const float* __restrict__ edge_e,
    const int* __restrict__ offsets, int* __restrict__ cursor,
    int* __restrict__ csr_e, int* __restrict__ csr_tgt, float* __restrict__ ee_perm,
    int E1, int E2)
{
    const int E = E1+E2;
    const int e = blockIdx.x*256 + threadIdx.x;
    if (e >= E) return;
    int src, tgt;
    if (e < E1) { src = edge[e]; tgt = edge[E1+e]; }
    else { const int e2 = e-E1; src = nhop[e2]; tgt = nhop[E2+e2]; }
    const int pos = atomicAdd(&cursor[src], 1);
    const int p = offsets[src] + pos;
    csr_e[p] = e;
    csr_tgt[p] = tgt;
    *(float4*)(ee_perm + (size_t)p*4) = *(const float4*)(edge_e + (size_t)e*4);
}

// per-node wave gather, depth-4 pipeline; computes rowsum internally.
__global__ __launch_bounds__(256) void k4_gather(
    const float* __restrict__ ee_perm, const int* __restrict__ offsets,
    const int* __restrict__ csr_e, const int* __restrict__ csr_tgt,
    const u16* __restrict__ emb_bf, const u16* __restrict__ tbl,
    const float* __restrict__ wsoft,
    float* __restrict__ pout, u16* __restrict__ semb_bf, float* __restrict__ rowsum3,
    int N)
{
    const int lane = threadIdx.x & 63;
    const int n = blockIdx.x*4 + (threadIdx.x >> 6);
    if (n >= N) return;
    const int hl = lane >> 4;
    const int hoff = hl*128 + (lane & 15)*8;

    union HT { u16x8 v; unsigned u[4]; };

    float acc[8];
    #pragma unroll
    for (int j = 0; j < 8; ++j) acc[j] = 0.f;
    float sm0=0.f, sm1=0.f, sm2=0.f, sm3=0.f;
    float rsl0=0.f, rsl1=0.f, rsl2=0.f, rsl3=0.f;

    const int start = offsets[n], end = offsets[n+1];
    for (int cb = start; cb < end; cb += 64) {
        const int rem = end - cb;
        const int cnt = rem < 64 ? rem : 64;    // wave-uniform
        int eL = 0, tgtL = 0;
        float4 eeL; eeL.x=0.f; eeL.y=0.f; eeL.z=0.f; eeL.w=0.f;
        if (lane < cnt) {
            eL   = csr_e[cb + lane];
            tgtL = csr_tgt[cb + lane];
            eeL  = *(const float4*)(ee_perm + (size_t)(cb + lane)*4);
        }
        rsl0 += eeL.x; rsl1 += eeL.y; rsl2 += eeL.z; rsl3 += eeL.w;
        const int cp = (cnt + 3) & ~3;

        HT ht0, ht1, ht2, ht3;
        u16 em0, em1, em2, em3;
#define K4_FETCH(J, IDX) { const int tg_ = __shfl(tgtL, (IDX)); const int eg_ = __shfl(eL, (IDX)); \
            ht##J.v = *(const u16x8*)(tbl + (size_t)tg_*1024 + 512 + hoff); \
            em##J = emb_bf[(size_t)eg_*64 + lane]; }
        K4_FETCH(0, 0) K4_FETCH(1, 1) K4_FETCH(2, 2) K4_FETCH(3, 3)

#define K4_STAGE(J) { \
            const float e0 = __shfl(eeL.x, i+J); \
            const float e1 = __shfl(eeL.y, i+J); \
            const float e2 = __shfl(eeL.z, i+J); \
            const float e3 = __shfl(eeL.w, i+J); \
            const float eh = (hl==0)?e0:(hl==1)?e1:(hl==2)?e2:e3; \
            _Pragma("unroll") \
            for (int p = 0; p < 4; ++p) { \
                union{unsigned u; float f;} lo_, hi_; \
                lo_.u = ht##J.u[p] << 16; hi_.u = ht##J.u[p] & 0xffff0000u; \
                acc[2*p]   += eh*lo_.f; \
                acc[2*p+1] += eh*hi_.f; \
            } \
            const float ev = bf2f(em##J); \
            sm0 += e0*ev; sm1 += e1*ev; sm2 += e2*ev; sm3 += e3*ev; \
            { const int ii = i + 4 + J; const int ic = ii < 63 ? ii : 63; K4_FETCH(J, ic) } }

        for (int i = 0; i < cp; i += 4) {
            K4_STAGE(0)
            K4_STAGE(1)
            K4_STAGE(2)
            K4_STAGE(3)
        }
#undef K4_STAGE
#undef K4_FETCH
    }

    // butterfly-reduce rowsum partials across the wave
    #pragma unroll
    for (int d = 1; d < 64; d <<= 1) {
        rsl0 += __shfl_xor(rsl0, d);
        rsl1 += __shfl_xor(rsl1, d);
        rsl2 += __shfl_xor(rsl2, d);
        rsl3 += __shfl_xor(rsl3, d);
    }
    // hsrc term: head_out += rowsum_h * hsrc[n]
    {
        const float rsh = (hl==0)?rsl0:(hl==1)?rsl1:(hl==2)?rsl2:rsl3;
        HT hs; hs.v = *(const u16x8*)(tbl + (size_t)n*1024 + hoff);
        #pragma unroll
        for (int p = 0; p < 4; ++p) {
            union{unsigned u; float f;} lo_, hi_;
            lo_.u = hs.u[p] << 16; hi_.u = hs.u[p] & 0xffff0000u;
            acc[2*p]   += rsh*lo_.f;
            acc[2*p+1] += rsh*hi_.f;
        }
    }
    if (lane == 0) rowsum3[n] = fmaxf(rsl3, 1e-12f);

    const float4 ws4 = *(const float4*)wsoft;
    const float wh = (hl==0)?ws4.x:(hl==1)?ws4.y:(hl==2)?ws4.z:ws4.w;
    float p[8];
    #pragma unroll
    for (int j = 0; j < 8; ++j) {
        float pv = wh*acc[j];
        pv += __shfl_xor(pv, 16);
        pv += __shfl_xor(pv, 32);
        p[j] = pv;
    }
    if (hl == 0) {
        float* op = pout + (size_t)n*128 + (lane & 15)*8;
        float4 A; A.x=p[0]; A.y=p[1]; A.z=p[2]; A.w=p[3];
        float4 B; B.x=p[4]; B.y=p[5]; B.z=p[6]; B.w=p[7];
        *(float4*)op = A;
        *(float4*)(op+4) = B;
    }
    u16* so = semb_bf + (size_t)n*256;
    so[lane]       = f2bf(ws4.x*sm0);
    so[64 + lane]  = f2bf(ws4.y*sm1);
    so[128 + lane] = f2bf(ws4.z*sm2);
    so[192 + lane] = f2bf(ws4.w*sm3);
}

// MFMA GEMM: out_add = semb_bf (N x 256) @ WcatT^T (256 x 128); fused epilogue.
__global__ __launch_bounds__(256) void k5_gemm(
    const u16* __restrict__ semb_bf, const u16* __restrict__ wcatT_bf,
    const float* __restrict__ rowsum3, const float* __restrict__ orth_part,
    float* __restrict__ out, int N)
{
    __shared__ float DS[64*132];
    const int tid = threadIdx.x;
    if (blockIdx.x == 0 && tid == 0)
        out[(size_t)N*128] = 0.01f*(sqrtf(orth_part[0])+sqrtf(orth_part[1])+sqrtf(orth_part[2])+sqrtf(orth_part[3]));
    const int w = tid >> 6, lane = tid & 63;
    const int m = lane & 15, kg = lane >> 4;
    const int n0 = blockIdx.x*64;

    bf16x8 fa[8];
    {
        int row = n0 + w*16 + m; if (row >= N) row = N-1;
        const u16* ap = semb_bf + (size_t)row*256 + kg*8;
        #pragma unroll
        for (int ks = 0; ks < 8; ++ks) fa[ks] = *(const bf16x8*)(ap + ks*32);
    }
    f32x4 acc[8];
    #pragma unroll
    for (int nt = 0; nt < 8; ++nt) { acc[nt][0]=0.f; acc[nt][1]=0.f; acc[nt][2]=0.f; acc[nt][3]=0.f; }
    #pragma unroll
    for (int nt = 0; nt < 8; ++nt) {
        const u16* bp = wcatT_bf + (size_t)(nt*16 + m)*256 + kg*8;
        #pragma unroll
        for (int ks = 0; ks < 8; ++ks) {
            const bf16x8 fb = *(const bf16x8*)(bp + ks*32);
            acc[nt] = __builtin_amdgcn_mfma_f32_16x16x32_bf16(fa[ks], fb, acc[nt], 0, 0, 0);
        }
    }
    #pragma unroll
    for (int nt = 0; nt < 8; ++nt) {
        const int o = nt*16 + m;
        const int r0 = w*16 + kg*4;
        #pragma unroll
        for (int r = 0; r < 4; ++r)
            DS[(r0+r)*132 + o] = acc[nt][r];
    }
    __syncthreads();
    for (int idx = tid; idx < 2048; idx += 256) {
        const int row = idx >> 5, q = idx & 31;
        const int n = n0 + row;
        if (n < N) {
            const float4 d = *(const float4*)&DS[row*132 + q*4];
            float* op = out + (size_t)n*128 + q*4;
            const float4 pv = *(const float4*)op;
            const float rinv = 1.0f / rowsum3[n];
            float v0 = (pv.x + d.x)*rinv;
            float v1 = (pv.y + d.y)*rinv;
            float v2 = (pv.z + d.z)*rinv;
            float v3 = (pv.w + d.w)*rinv;
            v0 = (v0 > 0.f) ? v0 : expm1f(v0);
            v1 = (v1 > 0.f) ? v1 : expm1f(v1);
            v2 = (v2 > 0.f) ? v2 : expm1f(v2);
            v3 = (v3 > 0.f) ? v3 : expm1f(v3);
            float4 r4; r4.x=v0; r4.y=v1; r4.z=v2; r4.w=v3;
            *(float4*)op = r4;
        }
    }
}

extern "C" void kernel_launch(void* const* d_in, const int* in_sizes, int n_in,
                              void* d_out, int out_size, void* d_ws, size_t ws_size,
                              hipStream_t stream)
{
    const float* input = (const float*)d_in[0];
    const int*   edge  = (const int*)d_in[1];
    const float* emb1  = (const float*)d_in[2];
    const int*   nhop  = (const int*)d_in[3];
    const float* emb2  = (const float*)d_in[4];
    const float* proj  = (const float*)d_in[5];
    const float* W     = (const float*)d_in[6];
    const float* a     = (const float*)d_in[7];
    const float* hw    = (const float*)d_in[8];
    float* out = (float*)d_out;

    const int N  = in_sizes[0] / 128;
    const int E1 = in_sizes[1] / 2;
    const int E2 = in_sizes[3] / 2;
    const int E  = E1 + E2;
    (void)n_in; (void)out_size; (void)ws_size;

    char* wsb = (char*)d_ws;
    size_t off = 0;
    auto alloc = [&](size_t bytes) -> char* {
        char* p = wsb + off;
        off += (bytes + 255) & ~(size_t)255;
        return p;
    };
    u16*   in_bf    = (u16*)alloc((size_t)N*128*2);
    u16*   tbl      = (u16*)alloc((size_t)N*1024*2);
    u16*   semb_bf  = (u16*)alloc((size_t)N*256*2);
    u16*   emb_bf   = (u16*)alloc((size_t)E*64*2);
    float* edge_e   = (float*)alloc((size_t)E*4*4);
    float* ee_perm  = (float*)alloc((size_t)E*4*4);
    int*   csr_e    = (int*)alloc((size_t)E*4);
    int*   csr_tgt  = (int*)alloc((size_t)E*4);
    u16*   M_bf     = (u16*)alloc((size_t)8*16384*2);
    u16*   WcatT_bf = (u16*)alloc((size_t)128*256*2);
    float* asrc     = (float*)alloc(512*4);
    float* atgt     = (float*)alloc(512*4);
    float* arel     = (float*)alloc(256*4);
    float* s_src    = (float*)alloc((size_t)N*4*4);
    float* s_tgt    = (float*)alloc((size_t)N*4*4);
    float* wsoft    = (float*)alloc(4*4);
    float* rowsum3  = (float*)alloc((size_t)N*4);
    int*   offsets  = (int*)alloc((size_t)(N+1)*4);
    int*   bsum     = (int*)alloc(64*4);
    int*   boff     = (int*)alloc(64*4);
    const size_t zoff0 = off;
    float* orth_part= (float*)alloc(4*4);
    int*   deg      = (int*)alloc((size_t)N*4);
    int*   cursor   = (int*)alloc((size_t)N*4);
    const size_t zoff1 = off;

    hipMemsetAsync(wsb + zoff0, 0, zoff1 - zoff0, stream);

    const int nbScan = (N + 4095) / 4096;

    k1_prep<<<dim3(NHEAD,3,4), dim3(256), 0, stream>>>(proj, W, a, hw, M_bf,
                                                       asrc, atgt, arel, WcatT_bf, wsoft, orth_part);
    k0_nodes<<<dim3((N+255)/256), dim3(256), 0, stream>>>(input, asrc, atgt, in_bf, s_src, s_tgt, N);
    k2_mfma<<<dim3((N+255)/256, 8), dim3(256), 0, stream>>>(in_bf, M_bf, tbl, N);
    k3_edges<<<dim3((E+255)/256), dim3(256), 0, stream>>>(edge, nhop, emb1, emb2, s_src, s_tgt,
                                                          arel, edge_e, deg, emb_bf, E1, E2);
    k_scanA<<<dim3(nbScan), dim3(1024), 0, stream>>>(deg, offsets, bsum, N);
    k_scanB<<<dim3(1), dim3(64), 0, stream>>>(bsum, boff, offsets, nbScan, N);
    k_scanC<<<dim3((N+255)/256), dim3(256), 0, stream>>>(offsets, boff, N);
    k_fill<<<dim3((E+255)/256), dim3(256), 0, stream>>>(edge, nhop, edge_e, offsets, cursor,
                                                        csr_e, csr_tgt, ee_perm, E1, E2);
    k4_gather<<<dim3((N+3)/4), dim3(256), 0, stream>>>(ee_perm, offsets, csr_e, csr_tgt, emb_bf,
                                                       tbl, wsoft, out, semb_bf, rowsum3, N);
    k5_gemm<<<dim3((N+63)/64), dim3(256), 0, stream>>>(semb_bf, WcatT_bf, rowsum3, orth_part,
                                                       out, N);
}

// Round 6
// 272.769 us; speedup vs baseline: 3.7619x; 1.0109x over previous
//
#include <hip/hip_runtime.h>
#include <math.h>

// SpGraphAttentionLayer on MI355X — round 6.
// k4: guarded (no-waste) depth-4 pipeline, bf16 pout; k2: XCD-chunked swizzle for
// A-tile L2 reuse; scanC folded into fill/k4 (boff added at use site).

#define NHEAD 4

typedef unsigned short u16;
typedef __attribute__((ext_vector_type(4))) unsigned short u16x4;
typedef __attribute__((ext_vector_type(8))) unsigned short u16x8;
typedef __attribute__((ext_vector_type(8))) short bf16x8;
typedef __attribute__((ext_vector_type(4))) float f32x4;

__device__ __forceinline__ float bf2f(u16 v) {
    union { unsigned u; float f; } x; x.u = ((unsigned)v) << 16; return x.f;
}
__device__ __forceinline__ u16 f2bf(float f) {
    union { float f; unsigned u; } x; x.f = f;
    const unsigned r = x.u + 0x7FFFu + ((x.u >> 16) & 1u);
    return (u16)(r >> 16);
}

__global__ __launch_bounds__(256) void k1_prep(
    const float* __restrict__ proj, const float* __restrict__ W,
    const float* __restrict__ a, const float* __restrict__ hw,
    u16* __restrict__ M_bf,
    float* __restrict__ asrc, float* __restrict__ atgt, float* __restrict__ arel,
    u16* __restrict__ WcatT_bf, float* __restrict__ wsoft,
    float* __restrict__ orth_part)
{
    __shared__ float projS[128*132];
    __shared__ float WS[32*132];
    __shared__ float tS[128];
    __shared__ float red[256];
    const int h = blockIdx.x;
    const int part = blockIdx.y;
    const int z = blockIdx.z;
    const int tid = threadIdx.x;
    const float* projH = proj + h*(128*128);
    const float* WH = W + h*(128*320);
    const float* aH = a + h*128;

    {
        const float4* p4 = (const float4*)projH;
        for (int idx = tid; idx < 4096; idx += 256)
            *(float4*)&projS[(idx>>5)*132 + (idx&31)*4] = p4[idx];
    }

    if (part < 2) {
        const int koff = part ? 128 : 0;
        for (int idx = tid; idx < 1024; idx += 256) {
            const int ol = idx>>5, jq = idx&31;
            *(float4*)&WS[ol*132 + jq*4] = *(const float4*)&WH[(z*32+ol)*320 + koff + jq*4];
        }
        __syncthreads();
        u16* Mout = M_bf + ((size_t)(part*4 + h))*16384;
        for (int idx = tid; idx < 1024; idx += 256) {
            const int ol = idx>>5, jq = idx&31;
            float4 acc; acc.x=0.f; acc.y=0.f; acc.z=0.f; acc.w=0.f;
            for (int i = 0; i < 128; ++i) {
                const float wv = WS[ol*132 + i];
                const float4 pv = *(const float4*)&projS[i*132 + jq*4];
                acc.x += wv*pv.x; acc.y += wv*pv.y; acc.z += wv*pv.z; acc.w += wv*pv.w;
            }
            u16x4 pk; pk.x=f2bf(acc.x); pk.y=f2bf(acc.y); pk.z=f2bf(acc.z); pk.w=f2bf(acc.w);
            *(u16x4*)&Mout[(z*32+ol)*128 + jq*4] = pk;
        }
        if (z == 0) {
            if (tid < 128) {
                float s = 0.f;
                for (int o = 0; o < 128; ++o) s += aH[o]*WH[o*320 + koff + tid];
                tS[tid] = s;
            }
            __syncthreads();
            if (tid < 128) {
                float s = 0.f;
                for (int i = 0; i < 128; ++i) s += tS[i]*projS[i*132 + tid];
                (part ? atgt : asrc)[h*128 + tid] = s;
            }
        }
    } else {
        __syncthreads();
        float local = 0.f;
        const int base = z*4096;
        for (int idx = base + tid; idx < base + 4096; idx += 256) {
            const int i = idx>>7, k = idx&127;
            float s = 0.f;
            for (int q = 0; q < 32; ++q) {
                const float4 pi = *(const float4*)&projS[i*132 + q*4];
                const float4 pk = *(const float4*)&projS[k*132 + q*4];
                s += pi.x*pk.x + pi.y*pk.y + pi.z*pk.z + pi.w*pk.w;
            }
            if (i == k) s -= 1.f;
            local += s*s;
        }
        red[tid] = local;
        __syncthreads();
        for (int st = 128; st > 0; st >>= 1) {
            if (tid < st) red[tid] += red[tid+st];
            __syncthreads();
        }
        if (tid == 0) atomicAdd(&orth_part[h], red[0]);
        if (z == 0) {
            if (tid < 64) {
                float s = 0.f;
                for (int o = 0; o < 128; ++o) s += aH[o]*WH[o*320 + 256 + tid];
                arel[h*64 + tid] = s;
            }
            for (int idx = tid; idx < 8192; idx += 256) {
                const int r = idx & 63, o = idx >> 6;
                WcatT_bf[(size_t)o*256 + h*64 + r] = f2bf(WH[o*320 + 256 + r]);
            }
            if (h == 0 && tid == 0) {
                const float m = fmaxf(fmaxf(hw[0],hw[1]), fmaxf(hw[2],hw[3]));
                const float e0=expf(hw[0]-m), e1=expf(hw[1]-m), e2=expf(hw[2]-m), e3=expf(hw[3]-m);
                const float s = e0+e1+e2+e3;
                wsoft[0]=e0/s; wsoft[1]=e1/s; wsoft[2]=e2/s; wsoft[3]=e3/s;
            }
        }
    }
}

// fused: input -> bf16 + per-node score partials
__global__ __launch_bounds__(256) void k0_nodes(
    const float* __restrict__ input, const float* __restrict__ asrc, const float* __restrict__ atgt,
    u16* __restrict__ in_bf, float* __restrict__ s_src, float* __restrict__ s_tgt, int N)
{
    __shared__ float aS[512], tS[512];
    const int tid = threadIdx.x;
    for (int idx = tid; idx < 512; idx += 256) { aS[idx] = asrc[idx]; tS[idx] = atgt[idx]; }
    __syncthreads();
    const int n = blockIdx.x*256 + tid;
    if (n >= N) return;
    const float4* inr = (const float4*)(input + (size_t)n*128);
    u16* ob = in_bf + (size_t)n*128;
    float ss[4] = {0.f,0.f,0.f,0.f}, st[4] = {0.f,0.f,0.f,0.f};
    for (int q = 0; q < 32; ++q) {
        const float4 v = inr[q];
        u16x4 pk; pk.x=f2bf(v.x); pk.y=f2bf(v.y); pk.z=f2bf(v.z); pk.w=f2bf(v.w);
        *(u16x4*)(ob + q*4) = pk;
        #pragma unroll
        for (int hh = 0; hh < 4; ++hh) {
            const float4 av = *(const float4*)&aS[hh*128 + q*4];
            const float4 tv = *(const float4*)&tS[hh*128 + q*4];
            ss[hh] += v.x*av.x + v.y*av.y + v.z*av.z + v.w*av.w;
            st[hh] += v.x*tv.x + v.y*tv.y + v.z*tv.z + v.w*tv.w;
        }
    }
    float4 o1; o1.x=ss[0]; o1.y=ss[1]; o1.z=ss[2]; o1.w=ss[3];
    float4 o2; o2.x=st[0]; o2.y=st[1]; o2.z=st[2]; o2.w=st[3];
    *(float4*)(s_src + (size_t)n*4) = o1;
    *(float4*)(s_tgt + (size_t)n*4) = o2;
}

// LDS-tiled MFMA GEMM, 1D grid with XCD-chunked swizzle: each XCD gets a
// contiguous run of (xtile, mat) work items -> A-tile re-reads hit its L2.
__global__ __launch_bounds__(256) void k2_mfma(
    const u16* __restrict__ in_bf, const u16* __restrict__ M_bf,
    u16* __restrict__ tbl, int N)
{
    __shared__ u16 MS[16384];
    __shared__ u16 DS[128*136];
    const int tid = threadIdx.x;
    const int w = tid >> 6, lane = tid & 63;
    const int bid = blockIdx.x;
    const int nx = gridDim.x >> 3;
    const int swz = (bid & 7)*nx + (bid >> 3);
    const int n0 = (swz >> 3)*256;
    const int mat = swz & 7;
    const int m = lane & 15, kg = lane >> 4;

    {
        const u16* Mp = M_bf + (size_t)mat*16384;
        for (int c = tid; c < 2048; c += 256) {
            const int row = c >> 4, c16 = c & 15;
            const u16x8 v = *(const u16x8*)(Mp + row*128 + c16*8);
            *(u16x8*)((char*)MS + row*256 + ((c16*16) ^ ((row&7)<<4))) = v;
        }
    }
    bf16x8 fa[4][4];
    #pragma unroll
    for (int rt = 0; rt < 4; ++rt) {
        int row = n0 + w*64 + rt*16 + m; if (row >= N) row = N-1;
        const u16* ap = in_bf + (size_t)row*128 + kg*8;
        #pragma unroll
        for (int ks = 0; ks < 4; ++ks) fa[rt][ks] = *(const bf16x8*)(ap + ks*32);
    }
    __syncthreads();

    f32x4 acc[4][8];
    #pragma unroll
    for (int rt = 0; rt < 4; ++rt)
        #pragma unroll
        for (int nt = 0; nt < 8; ++nt) { acc[rt][nt][0]=0.f; acc[rt][nt][1]=0.f; acc[rt][nt][2]=0.f; acc[rt][nt][3]=0.f; }

    #pragma unroll
    for (int nt = 0; nt < 8; ++nt) {
        const int o = nt*16 + m;
        bf16x8 fb[4];
        #pragma unroll
        for (int ks = 0; ks < 4; ++ks) {
            const int c16 = kg + 4*ks;
            fb[ks] = *(const bf16x8*)((const char*)MS + o*256 + ((c16*16) ^ ((o&7)<<4)));
        }
        #pragma unroll
        for (int rt = 0; rt < 4; ++rt)
            #pragma unroll
            for (int ks = 0; ks < 4; ++ks)
                acc[rt][nt] = __builtin_amdgcn_mfma_f32_16x16x32_bf16(fa[rt][ks], fb[ks], acc[rt][nt], 0, 0, 0);
    }

    for (int p = 0; p < 2; ++p) {
        __syncthreads();
        if ((w >> 1) == p) {
            #pragma unroll
            for (int rt = 0; rt < 4; ++rt) {
                const int r0 = (w&1)*64 + rt*16 + kg*4;
                #pragma unroll
                for (int nt = 0; nt < 8; ++nt) {
                    const int o = nt*16 + m;
                    #pragma unroll
                    for (int r = 0; r < 4; ++r)
                        DS[(r0+r)*136 + o] = f2bf(acc[rt][nt][r]);
                }
            }
        }
        __syncthreads();
        for (int idx = tid; idx < 2048; idx += 256) {
            const int row = idx >> 4, seg = idx & 15;
            const int n = n0 + p*128 + row;
            if (n < N) {
                const bf16x8 v = *(const bf16x8*)&DS[row*136 + seg*8];
                *(bf16x8*)(tbl + (size_t)n*1024 + mat*128 + seg*8) = v;
            }
        }
    }
}

// cooperative per-edge: 16 lanes per edge, coalesced emb reads
__global__ __launch_bounds__(256) void k3_edges(
    const int* __restrict__ edge, const int* __restrict__ nhop,
    const float* __restrict__ emb1, const float* __restrict__ emb2,
    const float* __restrict__ s_src, const float* __restrict__ s_tgt,
    const float* __restrict__ arel,
    float* __restrict__ edge_e, int* __restrict__ deg,
    u16* __restrict__ emb_bf, int E1, int E2)
{
    const int tid = threadIdx.x;
    const int g = tid >> 4, l = tid & 15;
    const int E = E1 + E2;
    const float4 ar0 = *(const float4*)(arel + 0*64 + l*4);
    const float4 ar1 = *(const float4*)(arel + 1*64 + l*4);
    const float4 ar2 = *(const float4*)(arel + 2*64 + l*4);
    const float4 ar3 = *(const float4*)(arel + 3*64 + l*4);
    const int ebase = blockIdx.x*256;
    #pragma unroll 4
    for (int it = 0; it < 16; ++it) {
        const int e = ebase + it*16 + g;
        if (e >= E) continue;
        const float4 v = (e < E1) ? *(const float4*)(emb1 + (size_t)e*64 + l*4)
                                  : *(const float4*)(emb2 + (size_t)(e-E1)*64 + l*4);
        u16x4 pk; pk.x=f2bf(v.x); pk.y=f2bf(v.y); pk.z=f2bf(v.z); pk.w=f2bf(v.w);
        *(u16x4*)(emb_bf + (size_t)e*64 + l*4) = pk;
        float p0 = v.x*ar0.x + v.y*ar0.y + v.z*ar0.z + v.w*ar0.w;
        float p1 = v.x*ar1.x + v.y*ar1.y + v.z*ar1.z + v.w*ar1.w;
        float p2 = v.x*ar2.x + v.y*ar2.y + v.z*ar2.z + v.w*ar2.w;
        float p3 = v.x*ar3.x + v.y*ar3.y + v.z*ar3.z + v.w*ar3.w;
        #pragma unroll
        for (int d = 1; d < 16; d <<= 1) {
            p0 += __shfl_xor(p0, d);
            p1 += __shfl_xor(p1, d);
            p2 += __shfl_xor(p2, d);
            p3 += __shfl_xor(p3, d);
        }
        if (l == 0) {
            int src, tgt;
            if (e < E1) { src = edge[e]; tgt = edge[E1+e]; }
            else { const int e2 = e-E1; src = nhop[e2]; tgt = nhop[E2+e2]; }
            const float4 s4 = *(const float4*)(s_src + (size_t)src*4);
            const float4 t4 = *(const float4*)(s_tgt + (size_t)tgt*4);
            float4 eo;
            { const float sc = s4.x+t4.x+p0; eo.x = expf(sc>0.f ? -sc : -0.2f*sc); }
            { const float sc = s4.y+t4.y+p1; eo.y = expf(sc>0.f ? -sc : -0.2f*sc); }
            { const float sc = s4.z+t4.z+p2; eo.z = expf(sc>0.f ? -sc : -0.2f*sc); }
            { const float sc = s4.w+t4.w+p3; eo.w = expf(sc>0.f ? -sc : -0.2f*sc); }
            *(float4*)(edge_e + (size_t)e*4) = eo;
            atomicAdd(&deg[src], 1);
        }
    }
}

__global__ __launch_bounds__(1024) void k_scanA(const int* __restrict__ deg, int* __restrict__ offsets,
                                                int* __restrict__ bsum, int N)
{
    __shared__ int wsumS[16];
    const int tid = threadIdx.x;
    const int lane = tid & 63, wid = tid >> 6;
    const int i0 = blockIdx.x*4096 + tid*4;
    int a0=0,a1=0,a2=0,a3=0;
    if (i0 + 3 < N) { const int4 t = *(const int4*)(deg + i0); a0=t.x; a1=t.y; a2=t.z; a3=t.w; }
    else { if (i0 < N) a0=deg[i0]; if (i0+1 < N) a1=deg[i0+1]; if (i0+2 < N) a2=deg[i0+2]; }
    const int s1=a0+a1, s2=s1+a2, s3=s2+a3;
    int s = s3;
    #pragma unroll
    for (int d = 1; d < 64; d <<= 1) { const int t = __shfl_up(s, d); if (lane >= d) s += t; }
    if (lane == 63) wsumS[wid] = s;
    __syncthreads();
    if (tid < 16) {
        int t = wsumS[tid];
        #pragma unroll
        for (int d = 1; d < 16; d <<= 1) { const int u = __shfl_up(t, d); if (tid >= d) t += u; }
        wsumS[tid] = t;
    }
    __syncthreads();
    const int ex = (wid ? wsumS[wid-1] : 0) + s - s3;
    if (i0 < N)     offsets[i0]   = ex;
    if (i0+1 < N)   offsets[i0+1] = ex + a0;
    if (i0+2 < N)   offsets[i0+2] = ex + s1;
    if (i0+3 < N)   offsets[i0+3] = ex + s2;
    if (tid == 0) bsum[blockIdx.x] = wsumS[15];
}

__global__ __launch_bounds__(64) void k_scanB(const int* __restrict__ bsum, int* __restrict__ boff,
                                              int* __restrict__ offsets, int nb, int N)
{
    const int tid = threadIdx.x;
    const int v = (tid < nb) ? bsum[tid] : 0;
    int s = v;
    #pragma unroll
    for (int d = 1; d < 64; d <<= 1) { const int t = __shfl_up(s, d); if (tid >= d) s += t; }
    if (tid < nb) boff[tid] = s - v;
    if (tid == 63) offsets[N] = s;
}

__global__ __launch_bounds__(256) void k_fill(
    const int* __restrict__ edge, const int* __restrict__ nhop,
    const float* __restrict__ edge_e,
    const int* __restrict__ offsets, const int* __restrict__ boff, int* __restrict__ cursor,
    int* __restrict__ csr_e, int* __restrict__ csr_tgt, float* __restrict__ ee_perm,
    int E1, int E2)
{
    const int E = E1+E2;
    const int e = blockIdx.x*256 + threadIdx.x;
    if (e >= E) return;
    int src, tgt;
    if (e < E1) { src = edge[e]; tgt = edge[E1+e]; }
    else { const int e2 = e-E1; src = nhop[e2]; tgt = nhop[E2+e2]; }
    const int pos = atomicAdd(&cursor[src], 1);
    const int p = offsets[src] + boff[src>>12] + pos;
    csr_e[p] = e;
    csr_tgt[p] = tgt;
    *(float4*)(ee_perm + (size_t)p*4) = *(const float4*)(edge_e + (size_t)e*4);
}

// per-node wave gather: guarded depth-4 pipeline (no wasted tbl fetches), bf16 pout.
__global__ __launch_bounds__(256) void k4_gather(
    const float* __restrict__ ee_perm, const int* __restrict__ offsets, const int* __restrict__ boff,
    const int* __restrict__ csr_e, const int* __restrict__ csr_tgt,
    const u16* __restrict__ emb_bf, const u16* __restrict__ tbl,
    const float* __restrict__ wsoft,
    u16* __restrict__ pout_bf, u16* __restrict__ semb_bf, float* __restrict__ rowsum3,
    int N)
{
    const int lane = threadIdx.x & 63;
    const int n = blockIdx.x*4 + (threadIdx.x >> 6);
    if (n >= N) return;
    const int hl = lane >> 4;
    const int hoff = hl*128 + (lane & 15)*8;

    union HT { u16x8 v; unsigned u[4]; };

    float acc[8];
    #pragma unroll
    for (int j = 0; j < 8; ++j) acc[j] = 0.f;
    float sm0=0.f, sm1=0.f, sm2=0.f, sm3=0.f;
    float rsl0=0.f, rsl1=0.f, rsl2=0.f, rsl3=0.f;

    const int start = offsets[n] + boff[n>>12];
    const int end = (n+1 == N) ? offsets[N] : (offsets[n+1] + boff[(n+1)>>12]);
    for (int cb = start; cb < end; cb += 64) {
        const int rem = end - cb;
        const int cnt = rem < 64 ? rem : 64;    // wave-uniform
        int eL = 0, tgtL = 0;
        float4 eeL; eeL.x=0.f; eeL.y=0.f; eeL.z=0.f; eeL.w=0.f;
        if (lane < cnt) {
            eL   = csr_e[cb + lane];
            tgtL = csr_tgt[cb + lane];
            eeL  = *(const float4*)(ee_perm + (size_t)(cb + lane)*4);
        }
        rsl0 += eeL.x; rsl1 += eeL.y; rsl2 += eeL.z; rsl3 += eeL.w;
        const int cp = (cnt + 3) & ~3;

        HT zz; zz.u[0]=0u; zz.u[1]=0u; zz.u[2]=0u; zz.u[3]=0u;
        HT ht0=zz, ht1=zz, ht2=zz, ht3=zz;
        u16 em0=0, em1=0, em2=0, em3=0;
#define K4_FETCH(J, IDX) { const int tg_ = __shfl(tgtL, (IDX)); const int eg_ = __shfl(eL, (IDX)); \
            ht##J.v = *(const u16x8*)(tbl + (size_t)tg_*1024 + 512 + hoff); \
            em##J = emb_bf[(size_t)eg_*64 + lane]; }
        if (0 < cnt) K4_FETCH(0, 0)
        if (1 < cnt) K4_FETCH(1, 1)
        if (2 < cnt) K4_FETCH(2, 2)
        if (3 < cnt) K4_FETCH(3, 3)

#define K4_STAGE(J) { \
            const float e0 = __shfl(eeL.x, i+J); \
            const float e1 = __shfl(eeL.y, i+J); \
            const float e2 = __shfl(eeL.z, i+J); \
            const float e3 = __shfl(eeL.w, i+J); \
            const float eh = (hl==0)?e0:(hl==1)?e1:(hl==2)?e2:e3; \
            _Pragma("unroll") \
            for (int p = 0; p < 4; ++p) { \
                union{unsigned u; float f;} lo_, hi_; \
                lo_.u = ht##J.u[p] << 16; hi_.u = ht##J.u[p] & 0xffff0000u; \
                acc[2*p]   += eh*lo_.f; \
                acc[2*p+1] += eh*hi_.f; \
            } \
            const float ev = bf2f(em##J); \
            sm0 += e0*ev; sm1 += e1*ev; sm2 += e2*ev; sm3 += e3*ev; \
            { const int ii = i + 4 + J; if (ii < cnt) K4_FETCH(J, ii) } }

        for (int i = 0; i < cp; i += 4) {
            K4_STAGE(0)
            K4_STAGE(1)
            K4_STAGE(2)
            K4_STAGE(3)
        }
#undef K4_STAGE
#undef K4_FETCH
    }

    #pragma unroll
    for (int d = 1; d < 64; d <<= 1) {
        rsl0 += __shfl_xor(rsl0, d);
        rsl1 += __shfl_xor(rsl1, d);
        rsl2 += __shfl_xor(rsl2, d);
        rsl3 += __shfl_xor(rsl3, d);
    }
    {
        const float rsh = (hl==0)?rsl0:(hl==1)?rsl1:(hl==2)?rsl2:rsl3;
        HT hs; hs.v = *(const u16x8*)(tbl + (size_t)n*1024 + hoff);
        #pragma unroll
        for (int p = 0; p < 4; ++p) {
            union{unsigned u; float f;} lo_, hi_;
            lo_.u = hs.u[p] << 16; hi_.u = hs.u[p] & 0xffff0000u;
            acc[2*p]   += rsh*lo_.f;
            acc[2*p+1] += rsh*hi_.f;
        }
    }
    if (lane == 0) rowsum3[n] = fmaxf(rsl3, 1e-12f);

    const float4 ws4 = *(const float4*)wsoft;
    const float wh = (hl==0)?ws4.x:(hl==1)?ws4.y:(hl==2)?ws4.z:ws4.w;
    float p[8];
    #pragma unroll
    for (int j = 0; j < 8; ++j) {
        float pv = wh*acc[j];
        pv += __shfl_xor(pv, 16);
        pv += __shfl_xor(pv, 32);
        p[j] = pv;
    }
    if (hl == 0) {
        u16 pk[8];
        #pragma unroll
        for (int j = 0; j < 8; ++j) pk[j] = f2bf(p[j]);
        *(u16x8*)(pout_bf + (size_t)n*128 + (lane & 15)*8) = *(u16x8*)pk;
    }
    u16* so = semb_bf + (size_t)n*256;
    so[lane]       = f2bf(ws4.x*sm0);
    so[64 + lane]  = f2bf(ws4.y*sm1);
    so[128 + lane] = f2bf(ws4.z*sm2);
    so[192 + lane] = f2bf(ws4.w*sm3);
}

// MFMA GEMM: out = elu((pout_bf + semb@WcatT^T) / rowsum3); orth scalar.
__global__ __launch_bounds__(256) void k5_gemm(
    const u16* __restrict__ semb_bf, const u16* __restrict__ wcatT_bf,
    const u16* __restrict__ pout_bf,
    const float* __restrict__ rowsum3, const float* __restrict__ orth_part,
    float* __restrict__ out, int N)
{
    __shared__ float DS[64*132];
    const int tid = threadIdx.x;
    if (blockIdx.x == 0 && tid == 0)
        out[(size_t)N*128] = 0.01f*(sqrtf(orth_part[0])+sqrtf(orth_part[1])+sqrtf(orth_part[2])+sqrtf(orth_part[3]));
    const int w = tid >> 6, lane = tid & 63;
    const int m = lane & 15, kg = lane >> 4;
    const int n0 = blockIdx.x*64;

    bf16x8 fa[8];
    {
        int row = n0 + w*16 + m; if (row >= N) row = N-1;
        const u16* ap = semb_bf + (size_t)row*256 + kg*8;
        #pragma unroll
        for (int ks = 0; ks < 8; ++ks) fa[ks] = *(const bf16x8*)(ap + ks*32);
    }
    f32x4 acc[8];
    #pragma unroll
    for (int nt = 0; nt < 8; ++nt) { acc[nt][0]=0.f; acc[nt][1]=0.f; acc[nt][2]=0.f; acc[nt][3]=0.f; }
    #pragma unroll
    for (int nt = 0; nt < 8; ++nt) {
        const u16* bp = wcatT_bf + (size_t)(nt*16 + m)*256 + kg*8;
        #pragma unroll
        for (int ks = 0; ks < 8; ++ks) {
            const bf16x8 fb = *(const bf16x8*)(bp + ks*32);
            acc[nt] = __builtin_amdgcn_mfma_f32_16x16x32_bf16(fa[ks], fb, acc[nt], 0, 0, 0);
        }
    }
    #pragma unroll
    for (int nt = 0; nt < 8; ++nt) {
        const int o = nt*16 + m;
        const int r0 = w*16 + kg*4;
        #pragma unroll
        for (int r = 0; r < 4; ++r)
            DS[(r0+r)*132 + o] = acc[nt][r];
    }
    __syncthreads();
    for (int idx = tid; idx < 2048; idx += 256) {
        const int row = idx >> 5, q = idx & 31;
        const int n = n0 + row;
        if (n < N) {
            const float4 d = *(const float4*)&DS[row*132 + q*4];
            const u16x4 pb = *(const u16x4*)(pout_bf + (size_t)n*128 + q*4);
            const float rinv = 1.0f / rowsum3[n];
            float v0 = (bf2f(pb.x) + d.x)*rinv;
            float v1 = (bf2f(pb.y) + d.y)*rinv;
            float v2 = (bf2f(pb.z) + d.z)*rinv;
            float v3 = (bf2f(pb.w) + d.w)*rinv;
            v0 = (v0 > 0.f) ? v0 : expm1f(v0);
            v1 = (v1 > 0.f) ? v1 : expm1f(v1);
            v2 = (v2 > 0.f) ? v2 : expm1f(v2);
            v3 = (v3 > 0.f) ? v3 : expm1f(v3);
            float4 r4; r4.x=v0; r4.y=v1; r4.z=v2; r4.w=v3;
            *(float4*)(out + (size_t)n*128 + q*4) = r4;
        }
    }
}

extern "C" void kernel_launch(void* const* d_in, const int* in_sizes, int n_in,
                              void* d_out, int out_size, void* d_ws, size_t ws_size,
                              hipStream_t stream)
{
    const float* input = (const float*)d_in[0];
    const int*   edge  = (const int*)d_in[1];
    const float* emb1  = (const float*)d_in[2];
    const int*   nhop  = (const int*)d_in[3];
    const float* emb2  = (const float*)d_in[4];
    const float* proj  = (const float*)d_in[5];
    const float* W     = (const float*)d_in[6];
    const float* a     = (const float*)d_in[7];
    const float* hw    = (const float*)d_in[8];
    float* out = (float*)d_out;

    const int N  = in_sizes[0] / 128;
    const int E1 = in_sizes[1] / 2;
    const int E2 = in_sizes[3] / 2;
    const int E  = E1 + E2;
    (void)n_in; (void)out_size; (void)ws_size;

    char* wsb = (char*)d_ws;
    size_t off = 0;
    auto alloc = [&](size_t bytes) -> char* {
        char* p = wsb + off;
        off += (bytes + 255) & ~(size_t)255;
        return p;
    };
    u16*   in_bf    = (u16*)alloc((size_t)N*128*2);
    u16*   tbl      = (u16*)alloc((size_t)N*1024*2);
    u16*   semb_bf  = (u16*)alloc((size_t)N*256*2);
    u16*   pout_bf  = (u16*)alloc((size_t)N*128*2);
    u16*   emb_bf   = (u16*)alloc((size_t)E*64*2);
    float* edge_e   = (float*)alloc((size_t)E*4*4);
    float* ee_perm  = (float*)alloc((size_t)E*4*4);
    int*   csr_e    = (int*)alloc((size_t)E*4);
    int*   csr_tgt  = (int*)alloc((size_t)E*4);
    u16*   M_bf     = (u16*)alloc((size_t)8*16384*2);
    u16*   WcatT_bf = (u16*)alloc((size_t)128*256*2);
    float* asrc     = (float*)alloc(512*4);
    float* atgt     = (float*)alloc(512*4);
    float* arel     = (float*)alloc(256*4);
    float* s_src    = (float*)alloc((size_t)N*4*4);
    float* s_tgt    = (float*)alloc((size_t)N*4*4);
    float* wsoft    = (float*)alloc(4*4);
    float* rowsum3  = (float*)alloc((size_t)N*4);
    int*   offsets  = (int*)alloc((size_t)(N+1)*4);
    int*   bsum     = (int*)alloc(64*4);
    int*   boff     = (int*)alloc(64*4);
    const size_t zoff0 = off;
    float* orth_part= (float*)alloc(4*4);
    int*   deg      = (int*)alloc((size_t)N*4);
    int*   cursor   = (int*)alloc((size_t)N*4);
    const size_t zoff1 = off;

    hipMemsetAsync(wsb + zoff0, 0, zoff1 - zoff0, stream);

    const int nbScan = (N + 4095) / 4096;
    const int nx = (N + 255) / 256;

    k1_prep<<<dim3(NHEAD,3,4), dim3(256), 0, stream>>>(proj, W, a, hw, M_bf,
                                                       asrc, atgt, arel, WcatT_bf, wsoft, orth_part);
    k0_nodes<<<dim3((N+255)/256), dim3(256), 0, stream>>>(input, asrc, atgt, in_bf, s_src, s_tgt, N);
    k2_mfma<<<dim3(nx*8), dim3(256), 0, stream>>>(in_bf, M_bf, tbl, N);
    k3_edges<<<dim3((E+255)/256), dim3(256), 0, stream>>>(edge, nhop, emb1, emb2, s_src, s_tgt,
                                                          arel, edge_e, deg, emb_bf, E1, E2);
    k_scanA<<<dim3(nbScan), dim3(1024), 0, stream>>>(deg, offsets, bsum, N);
    k_scanB<<<dim3(1), dim3(64), 0, stream>>>(bsum, boff, offsets, nbScan, N);
    k_fill<<<dim3((E+255)/256), dim3(256), 0, stream>>>(edge, nhop, edge_e, offsets, boff, cursor,
                                                        csr_e, csr_tgt, ee_perm, E1, E2);
    k4_gather<<<dim3((N+3)/4), dim3(256), 0, stream>>>(ee_perm, offsets, boff, csr_e, csr_tgt, emb_bf,
                                                       tbl, wsoft, pout_bf, semb_bf, rowsum3, N);
    k5_gemm<<<dim3((N+63)/64), dim3(256), 0, stream>>>(semb_bf, WcatT_bf, pout_bf, rowsum3, orth_part,
                                                       out, N);
}